// Round 2
// baseline (4593.441 us; speedup 1.0000x reference)
//
#include <hip/hip_runtime.h>
#include <hip/hip_bf16.h>

#define HF 128
#define GBM 32

typedef unsigned int uint32;
typedef unsigned short ushort16;

// ---- bf16 helpers (bit ops; bf16->f32 exact, f32->bf16 RNE) ----
__device__ __forceinline__ float bflo(uint32 u) { return __uint_as_float(u << 16); }
__device__ __forceinline__ float bfhi(uint32 u) { return __uint_as_float(u & 0xffff0000u); }
__device__ __forceinline__ ushort16 f2bf(float f) {
  uint32 u = __float_as_uint(f);
  return (ushort16)((u + 0x7fffu + ((u >> 16) & 1u)) >> 16);
}

// ---------------------------------------------------------------------------
// diag: ws too small -> encode ws_size in MB into the output (telemetry)
__global__ void diag_k(float* __restrict__ out, int n, float val) {
  int i = blockIdx.x * 256 + threadIdx.x;
  if (i < n) out[i] = val;
}

// init: BN scale/shift identity for layer 0, zero pool
__global__ void init_k(float* __restrict__ ss, float* __restrict__ pool, int Gn) {
  int idx = blockIdx.x * 256 + threadIdx.x;
  if (idx < 512) ss[idx] = (idx < 128 || (idx >= 256 && idx < 384)) ? 1.f : 0.f;
  int p = idx - 512;
  if (p >= 0 && p < Gn * HF) pool[p] = 0.f;
}

// fp32 -> bf16 conversion (vectorized: 4 floats -> uint2)
__global__ void conv_k(const float* __restrict__ in, ushort16* __restrict__ out, int n4) {
  int i = blockIdx.x * 256 + threadIdx.x;
  if (i >= n4) return;
  float4 v = ((const float4*)in)[i];
  uint2 p;
  p.x = (uint32)f2bf(v.x) | ((uint32)f2bf(v.y) << 16);
  p.y = (uint32)f2bf(v.z) | ((uint32)f2bf(v.w) << 16);
  ((uint2*)out)[i] = p;
}

// ---------------------------------------------------------------------------
// CSR build: count (into rp), exclusive scan (rp,cur), fill (cs)
__global__ void count_k(const int* __restrict__ ei, int E, int* __restrict__ rp) {
  int e = blockIdx.x * 256 + threadIdx.x;
  if (e < E) atomicAdd(&rp[ei[E + e]], 1);
}

__global__ __launch_bounds__(1024) void scan_k(int* __restrict__ rp, int* __restrict__ cur, int N) {
  __shared__ int sd[1024];
  int t = threadIdx.x;
  int chunk = (N + 1023) >> 10;
  int lo = t * chunk, hi = min(lo + chunk, N);
  int s = 0;
  for (int i = lo; i < hi; ++i) s += rp[i];
  sd[t] = s;
  __syncthreads();
  for (int off = 1; off < 1024; off <<= 1) {
    int v = (t >= off) ? sd[t - off] : 0;
    __syncthreads();
    sd[t] += v;
    __syncthreads();
  }
  int run = (t > 0) ? sd[t - 1] : 0;
  for (int i = lo; i < hi; ++i) {
    int c = rp[i];
    rp[i] = run; cur[i] = run;
    run += c;
  }
  if (t == 1023) rp[N] = sd[1023];
}

__global__ void fill_k(const int* __restrict__ ei, int E, int* __restrict__ cur,
                       int* __restrict__ cs) {
  int e = blockIdx.x * 256 + threadIdx.x;
  if (e >= E) return;
  int dst = ei[E + e];
  int pos = atomicAdd(&cur[dst], 1);
  cs[pos] = ei[e];
}

// ---------------------------------------------------------------------------
// per-layer prep: 5 transposed weight mats [k][f], combined root for type a,
// combined bias for type a, zero BN stats
__global__ void prep_k(const float* __restrict__ Wrel_l, const float* __restrict__ Wroot_l,
                       const float* __restrict__ brel_l,
                       float* __restrict__ wt, float* __restrict__ bias_a,
                       float* __restrict__ stats) {
  int idx = blockIdx.x * 256 + threadIdx.x;
  if (idx < 81920) {
    int m = idx >> 14;          // which output matrix
    int r = idx & 16383;
    int k = r >> 7, f = r & 127;
    int src = f * HF + k;       // transpose
    float v;
    if (m == 0)      v = Wrel_l[src];                              // Wrel[l,0]^T
    else if (m == 1) v = Wrel_l[2 * 16384 + src];                  // Wrel[l,2]^T
    else if (m == 2) v = Wroot_l[src] + Wroot_l[2 * 16384 + src];  // (Wroot0+Wroot2)^T
    else if (m == 3) v = Wrel_l[16384 + src];                      // Wrel[l,1]^T
    else             v = Wroot_l[16384 + src];                     // Wroot[l,1]^T
    wt[idx] = v;
  } else if (idx < 82048) {
    int j = idx - 81920;
    bias_a[j] = brel_l[j] + brel_l[256 + j];
  } else if (idx < 82560) {
    stats[idx - 82048] = 0.f;
  }
}

// ---------------------------------------------------------------------------
// gather-fused GEMM:
//   out = relu( aggr1@Wt0 + [aggr2@Wt1] + bn(xr)@Wt2 + bias ), bf16 store,
//   BN stats accumulated. aggr_i built from CSR gather: sc*Sum(x_src)+deg*sh.
__global__ __launch_bounds__(256) void gg_k(
    const ushort16* __restrict__ Xg1, const int* __restrict__ rp1, const int* __restrict__ cs1,
    const float* __restrict__ ss1,
    const ushort16* __restrict__ Xg2, const int* __restrict__ rp2, const int* __restrict__ cs2,
    const float* __restrict__ ss2,
    const ushort16* __restrict__ Xr, const float* __restrict__ ssr,
    const float* __restrict__ Wt0, const float* __restrict__ Wt1, const float* __restrict__ Wt2,
    const float* __restrict__ bias,
    ushort16* __restrict__ out, float* __restrict__ stat_s, float* __restrict__ stat_q,
    int nRows) {
  __shared__ float sA[3][GBM][132];
  int tid = threadIdx.x;
  int m0 = blockIdx.x * GBM;
  int wv = tid >> 6, lane = tid & 63;

  // ---- gather phase: wave wv builds rows wv*8 .. wv*8+7 ----
  for (int rr = 0; rr < 8; ++rr) {
    int r = wv * 8 + rr;
    int gr = m0 + r;
    bool ok = gr < nRows;
    // tile 0
    {
      float a0 = 0.f, a1 = 0.f; int deg = 0;
      if (ok) {
        int e0 = rp1[gr], e1 = rp1[gr + 1];
        deg = e1 - e0;
        for (int e = e0; e < e1; ++e) {
          int s = cs1[e];
          uint32 u = ((const uint32*)Xg1)[(size_t)s * 64 + lane];
          a0 += bflo(u); a1 += bfhi(u);
        }
      }
      float2 o;
      o.x = a0 * ss1[2 * lane]     + (float)deg * ss1[128 + 2 * lane];
      o.y = a1 * ss1[2 * lane + 1] + (float)deg * ss1[128 + 2 * lane + 1];
      *(float2*)&sA[0][r][2 * lane] = o;
    }
    // tile 1 (optional)
    if (Xg2) {
      float a0 = 0.f, a1 = 0.f; int deg = 0;
      if (ok) {
        int e0 = rp2[gr], e1 = rp2[gr + 1];
        deg = e1 - e0;
        for (int e = e0; e < e1; ++e) {
          int s = cs2[e];
          uint32 u = ((const uint32*)Xg2)[(size_t)s * 64 + lane];
          a0 += bflo(u); a1 += bfhi(u);
        }
      }
      float2 o;
      o.x = a0 * ss2[2 * lane]     + (float)deg * ss2[128 + 2 * lane];
      o.y = a1 * ss2[2 * lane + 1] + (float)deg * ss2[128 + 2 * lane + 1];
      *(float2*)&sA[1][r][2 * lane] = o;
    }
    // tile 2: root (bn applied)
    {
      float2 o = make_float2(0.f, 0.f);
      if (ok) {
        uint32 u = ((const uint32*)Xr)[(size_t)gr * 64 + lane];
        o.x = bflo(u) * ssr[2 * lane]     + ssr[128 + 2 * lane];
        o.y = bfhi(u) * ssr[2 * lane + 1] + ssr[128 + 2 * lane + 1];
      }
      *(float2*)&sA[2][r][2 * lane] = o;
    }
  }
  __syncthreads();

  // ---- GEMM phase: thread = 4 rows x 4 cols ----
  int tx = tid & 31, ty = tid >> 5;
  float acc[4][4] = {{0.f}};
  const float* Wts[3] = {Wt0, Wt1, Wt2};
  for (int t = 0; t < 3; ++t) {
    const float* W = Wts[t];
    if (!W) continue;
    for (int k = 0; k < HF; k += 4) {
      float4 w0 = *(const float4*)&W[(k + 0) * HF + 4 * tx];
      float4 w1 = *(const float4*)&W[(k + 1) * HF + 4 * tx];
      float4 w2 = *(const float4*)&W[(k + 2) * HF + 4 * tx];
      float4 w3 = *(const float4*)&W[(k + 3) * HF + 4 * tx];
      #pragma unroll
      for (int i = 0; i < 4; ++i) {
        float4 a = *(const float4*)&sA[t][4 * ty + i][k];
        acc[i][0] += a.x * w0.x + a.y * w1.x + a.z * w2.x + a.w * w3.x;
        acc[i][1] += a.x * w0.y + a.y * w1.y + a.z * w2.y + a.w * w3.y;
        acc[i][2] += a.x * w0.z + a.y * w1.z + a.z * w2.z + a.w * w3.z;
        acc[i][3] += a.x * w0.w + a.y * w1.w + a.z * w2.w + a.w * w3.w;
      }
    }
  }

  // ---- epilogue: bias + relu + bf16 store + BN stats ----
  float4 bs = *(const float4*)&bias[4 * tx];
  float ps[4] = {0.f, 0.f, 0.f, 0.f}, pq[4] = {0.f, 0.f, 0.f, 0.f};
  #pragma unroll
  for (int i = 0; i < 4; ++i) {
    int gr = m0 + 4 * ty + i;
    float v0 = fmaxf(acc[i][0] + bs.x, 0.f);
    float v1 = fmaxf(acc[i][1] + bs.y, 0.f);
    float v2 = fmaxf(acc[i][2] + bs.z, 0.f);
    float v3 = fmaxf(acc[i][3] + bs.w, 0.f);
    if (gr < nRows) {
      uint2 p;
      p.x = (uint32)f2bf(v0) | ((uint32)f2bf(v1) << 16);
      p.y = (uint32)f2bf(v2) | ((uint32)f2bf(v3) << 16);
      *(uint2*)&out[(size_t)gr * HF + 4 * tx] = p;
      ps[0] += v0; ps[1] += v1; ps[2] += v2; ps[3] += v3;
      pq[0] += v0 * v0; pq[1] += v1 * v1; pq[2] += v2 * v2; pq[3] += v3 * v3;
    }
  }
  __syncthreads();
  float* red1 = &sA[0][0][0];
  float* red2 = red1 + 1024;
  #pragma unroll
  for (int j = 0; j < 4; ++j) {
    red1[ty * 128 + 4 * tx + j] = ps[j];
    red2[ty * 128 + 4 * tx + j] = pq[j];
  }
  __syncthreads();
  if (tid < 128) {
    float s = 0.f, q = 0.f;
    #pragma unroll
    for (int t2 = 0; t2 < 8; ++t2) { s += red1[t2 * 128 + tid]; q += red2[t2 * 128 + tid]; }
    unsafeAtomicAdd(&stat_s[tid], s);
    unsafeAtomicAdd(&stat_q[tid], q);
  }
}

// ---------------------------------------------------------------------------
__global__ void bn_fin_k(const float* __restrict__ stats, const float* __restrict__ gamma,
                         const float* __restrict__ beta, float* __restrict__ ss,
                         float nA, float nB) {
  int t = threadIdx.x;
  if (t >= 256) return;
  int type = t >> 7, f = t & 127;
  float nN = type ? nB : nA;
  float s = stats[type * 256 + f];
  float q = stats[type * 256 + 128 + f];
  float mean = s / nN;
  float var = q / nN - mean * mean;
  float rstd = rsqrtf(var + 1e-5f);
  float sc = gamma[type * HF + f] * rstd;
  float sh = beta[type * HF + f] - mean * sc;
  ss[type * 256 + f] = sc;
  ss[type * 256 + 128 + f] = sh;
}

// pooling over sorted batch ids (bf16 x, lazy BN)
__global__ __launch_bounds__(256) void pool_k(const ushort16* __restrict__ x,
                                              const int* __restrict__ batch,
                                              const float* __restrict__ scale,
                                              const float* __restrict__ shift,
                                              float* __restrict__ pool, int nN) {
  int start = blockIdx.x * 256;
  int f = threadIdx.x & 127;
  int sub = threadIdx.x >> 7;
  float sc = scale[f], sh = shift[f];
  float acc = 0.f;
  int cur = -1;
  int end = min(start + 256, nN);
  for (int n = start + sub; n < end; n += 2) {
    int g = batch[n];
    if (g != cur) {
      if (cur >= 0) unsafeAtomicAdd(&pool[(size_t)cur * HF + f], acc);
      acc = 0.f; cur = g;
    }
    float xv = __uint_as_float(((uint32)x[(size_t)n * HF + f]) << 16);
    acc += xv * sc + sh;
  }
  if (cur >= 0) unsafeAtomicAdd(&pool[(size_t)cur * HF + f], acc);
}

__device__ inline int lowerb(const int* a, int n, int v) {
  int lo = 0, hi = n;
  while (lo < hi) { int m = (lo + hi) >> 1; if (a[m] < v) lo = m + 1; else hi = m; }
  return lo;
}

__global__ void counts_k(const int* __restrict__ ba, int nA, const int* __restrict__ bb, int nB,
                         float* __restrict__ counts, int Gn) {
  for (int g = threadIdx.x; g < Gn; g += blockDim.x) {
    int c = (lowerb(ba, nA, g + 1) - lowerb(ba, nA, g)) +
            (lowerb(bb, nB, g + 1) - lowerb(bb, nB, g));
    counts[g] = fmaxf((float)c, 1.f);
  }
}

__global__ void final_k(const float* __restrict__ pool, const float* __restrict__ counts,
                        const float* __restrict__ linW, const float* __restrict__ linb,
                        float* __restrict__ out, int Cn) {
  int g = blockIdx.x;
  int lane = threadIdx.x;
  float inv = 1.f / counts[g];
  float p0 = pool[(size_t)g * HF + lane] * inv;
  float p1 = pool[(size_t)g * HF + 64 + lane] * inv;
  for (int c = 0; c < Cn; ++c) {
    float t = p0 * linW[c * HF + lane] + p1 * linW[c * HF + 64 + lane];
    for (int off = 32; off > 0; off >>= 1) t += __shfl_down(t, off);
    if (lane == 0) out[g * Cn + c] = t + linb[c];
  }
}

// ---------------------------------------------------------------------------
extern "C" void kernel_launch(void* const* d_in, const int* in_sizes, int n_in,
                              void* d_out, int out_size, void* d_ws, size_t ws_size,
                              hipStream_t stream) {
  const float* x_a   = (const float*)d_in[0];
  const float* x_b   = (const float*)d_in[1];
  const float* Wrel  = (const float*)d_in[2];
  const float* brel  = (const float*)d_in[3];
  const float* Wroot = (const float*)d_in[4];
  const float* bn_g  = (const float*)d_in[5];
  const float* bn_b  = (const float*)d_in[6];
  const float* lin_W = (const float*)d_in[7];
  const float* lin_b = (const float*)d_in[8];
  const int* ei_aa   = (const int*)d_in[9];
  const int* ei_ab   = (const int*)d_in[10];
  const int* ei_ba   = (const int*)d_in[11];
  const int* batch_a = (const int*)d_in[12];
  const int* batch_b = (const int*)d_in[13];

  int Na  = in_sizes[0] / HF;
  int Nb  = in_sizes[1] / HF;
  int Eaa = in_sizes[9] / 2;
  int Eab = in_sizes[10] / 2;
  int Eba = in_sizes[11] / 2;
  int Cn  = in_sizes[7] / HF;
  int Gn  = out_size / Cn;

  size_t NHa = (size_t)Na * HF, NHb = (size_t)Nb * HF;
  char* base = (char*)d_ws;
  auto alignup = [](size_t x) { return (x + 255) & ~(size_t)255; };
  size_t off = 0;
  size_t oXA0 = off; off = alignup(off + NHa * 2);
  size_t oXA1 = off; off = alignup(off + NHa * 2);
  size_t oXB  = off; off = alignup(off + NHb * 2);
  size_t oRP  = off; off = alignup(off + ((size_t)(Na + 1) + (Nb + 1) + (Na + 1)) * 4);
  size_t oCUR = off; off = alignup(off + ((size_t)Na + Nb + Na) * 4);
  size_t oCS  = off; off = alignup(off + ((size_t)Eaa + Eab + Eba) * 4);
  size_t oWT  = off; off = alignup(off + 5 * 16384 * 4);
  size_t oBIA = off; off = alignup(off + 128 * 4);
  size_t oSS  = off; off = alignup(off + 512 * 4);
  size_t oST  = off; off = alignup(off + 512 * 4);
  size_t oPOOL= off; off = alignup(off + (size_t)Gn * HF * 4);
  size_t oCNT = off; off = alignup(off + (size_t)Gn * 4);
  size_t need = off;

  if (ws_size < need) {
    // telemetry: report ws_size in MB through the output
    diag_k<<<(out_size + 255) / 256, 256, 0, stream>>>(
        (float*)d_out, out_size, (float)((double)ws_size / 1048576.0));
    return;
  }

  ushort16* XA0 = (ushort16*)(base + oXA0);
  ushort16* XA1 = (ushort16*)(base + oXA1);
  ushort16* XB  = (ushort16*)(base + oXB);
  int* rp_aa = (int*)(base + oRP);
  int* rp_ab = rp_aa + (Na + 1);
  int* rp_ba = rp_ab + (Nb + 1);
  int* cur_aa = (int*)(base + oCUR);
  int* cur_ab = cur_aa + Na;
  int* cur_ba = cur_ab + Nb;
  int* cs_aa = (int*)(base + oCS);
  int* cs_ab = cs_aa + Eaa;
  int* cs_ba = cs_ab + Eab;
  float* wt     = (float*)(base + oWT);
  float* bias_a = (float*)(base + oBIA);
  float* ss     = (float*)(base + oSS);
  float* stats  = (float*)(base + oST);
  float* pool   = (float*)(base + oPOOL);
  float* counts = (float*)(base + oCNT);

  float* ss_a = ss;            // scale[128], shift[128]
  float* ss_b = ss + 256;

  // init + input conversion to bf16
  init_k<<<(512 + Gn * HF + 255) / 256, 256, 0, stream>>>(ss, pool, Gn);
  conv_k<<<((int)(NHa / 4) + 255) / 256, 256, 0, stream>>>(x_a, XA0, (int)(NHa / 4));
  conv_k<<<((int)(NHb / 4) + 255) / 256, 256, 0, stream>>>(x_b, XB, (int)(NHb / 4));

  // CSR build (once per call, reused across layers)
  hipMemsetAsync(rp_aa, 0, ((size_t)(Na + 1) + (Nb + 1) + (Na + 1)) * 4, stream);
  count_k<<<(Eaa + 255) / 256, 256, 0, stream>>>(ei_aa, Eaa, rp_aa);
  count_k<<<(Eab + 255) / 256, 256, 0, stream>>>(ei_ab, Eab, rp_ab);
  count_k<<<(Eba + 255) / 256, 256, 0, stream>>>(ei_ba, Eba, rp_ba);
  scan_k<<<1, 1024, 0, stream>>>(rp_aa, cur_aa, Na);
  scan_k<<<1, 1024, 0, stream>>>(rp_ab, cur_ab, Nb);
  scan_k<<<1, 1024, 0, stream>>>(rp_ba, cur_ba, Na);
  fill_k<<<(Eaa + 255) / 256, 256, 0, stream>>>(ei_aa, Eaa, cur_aa, cs_aa);
  fill_k<<<(Eab + 255) / 256, 256, 0, stream>>>(ei_ab, Eab, cur_ab, cs_ab);
  fill_k<<<(Eba + 255) / 256, 256, 0, stream>>>(ei_ba, Eba, cur_ba, cs_ba);

  ushort16* xa_cur = XA0;
  ushort16* xa_nxt = XA1;
  for (int l = 0; l < 3; ++l) {
    const float* Wrel_l  = Wrel  + (size_t)l * 3 * 16384;
    const float* Wroot_l = Wroot + (size_t)l * 3 * 16384;
    const float* brel_l  = brel  + (size_t)l * 3 * HF;
    const float* bias_b  = brel_l + HF;   // brel[l,1]

    prep_k<<<(82560 + 255) / 256, 256, 0, stream>>>(Wrel_l, Wroot_l, brel_l,
                                                    wt, bias_a, stats);
    // type a: gathers xa (aa) + xb (ba); writes xa_nxt.  MUST run before gg_b
    // overwrites XB (it reads old XB).
    gg_k<<<(Na + GBM - 1) / GBM, 256, 0, stream>>>(
        xa_cur, rp_aa, cs_aa, ss_a,
        XB,     rp_ba, cs_ba, ss_b,
        xa_cur, ss_a,
        wt, wt + 16384, wt + 32768, bias_a,
        xa_nxt, stats, stats + 128, Na);
    // type b: gathers xa (ab); root = own XB rows; writes XB in-place.
    gg_k<<<(Nb + GBM - 1) / GBM, 256, 0, stream>>>(
        xa_cur, rp_ab, cs_ab, ss_a,
        nullptr, nullptr, nullptr, nullptr,
        XB, ss_b,
        wt + 49152, nullptr, wt + 65536, bias_b,
        XB, stats + 256, stats + 384, Nb);

    bn_fin_k<<<1, 256, 0, stream>>>(stats, bn_g, bn_b, ss, (float)Na, (float)Nb);

    ushort16* t = xa_cur; xa_cur = xa_nxt; xa_nxt = t;
  }

  pool_k<<<(Na + 255) / 256, 256, 0, stream>>>(xa_cur, batch_a, ss_a, ss_a + 128, pool, Na);
  pool_k<<<(Nb + 255) / 256, 256, 0, stream>>>(XB, batch_b, ss_b, ss_b + 128, pool, Nb);
  counts_k<<<1, 256, 0, stream>>>(batch_a, Na, batch_b, Nb, counts, Gn);
  final_k<<<Gn, 64, 0, stream>>>(pool, counts, lin_W, lin_b, (float*)d_out, Cn);
}

// Round 3
// 2902.524 us; speedup vs baseline: 1.5826x; 1.5826x over previous
//
#include <hip/hip_runtime.h>
#include <hip/hip_bf16.h>

#define HF 128

typedef unsigned int uint32;
typedef unsigned short ushort16;
typedef float f32x4 __attribute__((ext_vector_type(4)));
typedef __bf16 bf16x8 __attribute__((ext_vector_type(8)));

// ---- bf16 helpers ----
__device__ __forceinline__ float bflo(uint32 u) { return __uint_as_float(u << 16); }
__device__ __forceinline__ float bfhi(uint32 u) { return __uint_as_float(u & 0xffff0000u); }
__device__ __forceinline__ ushort16 f2bf(float f) {
  uint32 u = __float_as_uint(f);
  return (ushort16)((u + 0x7fffu + ((u >> 16) & 1u)) >> 16);
}
__device__ __forceinline__ uint32 pack2(float lo, float hi) {
  return (uint32)f2bf(lo) | ((uint32)f2bf(hi) << 16);
}

// ---------------------------------------------------------------------------
__global__ void diag_k(float* __restrict__ out, int n, float val) {
  int i = blockIdx.x * 256 + threadIdx.x;
  if (i < n) out[i] = val;
}

// init: BN scale/shift identity for layer 0, zero pool
__global__ void init_k(float* __restrict__ ss, float* __restrict__ pool, int Gn) {
  int idx = blockIdx.x * 256 + threadIdx.x;
  if (idx < 512) ss[idx] = (idx < 128 || (idx >= 256 && idx < 384)) ? 1.f : 0.f;
  int p = idx - 512;
  if (p >= 0 && p < Gn * HF) pool[p] = 0.f;
}

// fp32 -> bf16 conversion
__global__ void conv_k(const float* __restrict__ in, uint32* __restrict__ out, int n4) {
  int i = blockIdx.x * 256 + threadIdx.x;
  if (i >= n4) return;
  float4 v = ((const float4*)in)[i];
  uint2 p;
  p.x = pack2(v.x, v.y);
  p.y = pack2(v.z, v.w);
  ((uint2*)out)[i] = p;
}

// ---------------------------------------------------------------------------
// CSR build
__global__ void count_k(const int* __restrict__ ei, int E, int* __restrict__ rp) {
  int e = blockIdx.x * 256 + threadIdx.x;
  if (e < E) atomicAdd(&rp[ei[E + e]], 1);
}

__global__ __launch_bounds__(1024) void scan_k(int* __restrict__ rp, int* __restrict__ cur, int N) {
  __shared__ int sd[1024];
  int t = threadIdx.x;
  int chunk = (N + 1023) >> 10;
  int lo = t * chunk, hi = min(lo + chunk, N);
  int s = 0;
  for (int i = lo; i < hi; ++i) s += rp[i];
  sd[t] = s;
  __syncthreads();
  for (int off = 1; off < 1024; off <<= 1) {
    int v = (t >= off) ? sd[t - off] : 0;
    __syncthreads();
    sd[t] += v;
    __syncthreads();
  }
  int run = (t > 0) ? sd[t - 1] : 0;
  for (int i = lo; i < hi; ++i) {
    int c = rp[i];
    rp[i] = run; cur[i] = run;
    run += c;
  }
  if (t == 1023) rp[N] = sd[1023];
}

__global__ void fill_k(const int* __restrict__ ei, int E, int* __restrict__ cur,
                       int* __restrict__ cs) {
  int e = blockIdx.x * 256 + threadIdx.x;
  if (e >= E) return;
  int dst = ei[E + e];
  int pos = atomicAdd(&cur[dst], 1);
  cs[pos] = ei[e];
}

// ---------------------------------------------------------------------------
// per-layer prep: pack 5 weight mats into MFMA B-fragment order (bf16), with
// BN scale folded into k-columns; compute u-vectors (shift @ W^T) and biases.
// BWa: 12 ksteps (ks0-3: scA*Wrel0, ks4-7: scB*Wrel2, ks8-11: scA*(Wroot0+Wroot2))
// BWb: 8 ksteps  (ks0-3: scA*Wrel1, ks4-7: scB*Wroot1)
// uvec: [0]=uaa [1]=uba [2]=uab [3]=bias_a [4]=bias_b  (each 128 f32)
__global__ __launch_bounds__(128) void prep2_k(
    const float* __restrict__ Wrel_l, const float* __restrict__ Wroot_l,
    const float* __restrict__ brel_l, const float* __restrict__ ss,
    ushort16* __restrict__ BWa, ushort16* __restrict__ BWb,
    float* __restrict__ uvec) {
  __shared__ float red[128];
  int n = blockIdx.x, k = threadIdx.x;
  float scA = ss[k], shA = ss[128 + k], scB = ss[256 + k], shB = ss[384 + k];
  float w0  = Wrel_l[n * HF + k];
  float w1  = Wrel_l[16384 + n * HF + k];
  float w2  = Wrel_l[32768 + n * HF + k];
  float wr1 = Wroot_l[16384 + n * HF + k];
  float wrc = Wroot_l[n * HF + k] + Wroot_l[32768 + n * HF + k];

  int ksl = k >> 5;
  int lane = (n & 15) + (((k >> 3) & 3) << 4);
  int j = k & 7;
  int nt = n >> 4;
  auto put = [&](ushort16* B, int ksb, float v) {
    B[((size_t)((ksb + ksl) * 8 + nt) * 64 + lane) * 8 + j] = f2bf(v);
  };
  put(BWa, 0, scA * w0);
  put(BWa, 4, scB * w2);
  put(BWa, 8, scA * wrc);
  put(BWb, 0, scA * w1);
  put(BWb, 4, scB * wr1);

  auto reduce = [&](float v) -> float {
    red[k] = v;
    __syncthreads();
    for (int s = 64; s > 0; s >>= 1) {
      if (k < s) red[k] += red[k + s];
      __syncthreads();
    }
    float r = red[0];
    __syncthreads();
    return r;
  };
  float r0 = reduce(shA * w0);    // uaa
  float r1 = reduce(shB * w2);    // uba
  float r2 = reduce(shA * w1);    // uab
  float r3 = reduce(shA * wrc);   // bias_a extra
  float r4 = reduce(shB * wr1);   // bias_b extra
  if (k == 0) {
    uvec[n]       = r0;
    uvec[128 + n] = r1;
    uvec[256 + n] = r2;
    uvec[384 + n] = brel_l[n] + brel_l[256 + n] + r3;
    uvec[512 + n] = brel_l[128 + n] + r4;
  }
}

// ---------------------------------------------------------------------------
// fused gather + MFMA GEMM + epilogue. 256 threads = 4 independent waves,
// each owns 16 output rows. No barriers.
template <bool HAS2>
__global__ __launch_bounds__(256) void gg_k(
    const uint32* __restrict__ Xg1, const int* __restrict__ rp1, const int* __restrict__ cs1,
    const uint32* __restrict__ Xg2, const int* __restrict__ rp2, const int* __restrict__ cs2,
    const uint32* Xr,                       // no restrict: may alias out (type b)
    const bf16x8* __restrict__ BW,
    const float* __restrict__ u1, const float* __restrict__ u2,
    const float* __restrict__ bias,
    uint32* out,
    float* __restrict__ statS, float* __restrict__ statQ,
    int nRows) {
  constexpr int TILE_DW = HAS2 ? 128 : 64;   // dwords per LDS row (gather layout)
  constexpr int KS_G = HAS2 ? 8 : 4;         // gathered k-steps
  constexpr int WDW = HAS2 ? 2048 : 1088;    // per-wave LDS dwords
  __shared__ uint32 lds[4][WDW];
  int tid = threadIdx.x, wid = tid >> 6, l = tid & 63;
  int R0 = blockIdx.x * 64 + wid * 16;
  uint32* L = &lds[wid][0];

  // ---- gather phase: rows R0..R0+15, pure bf16 row-sum, swizzled LDS ----
  for (int r = 0; r < 16; ++r) {
    int gr = R0 + r;
    int swz = (r & 7) << 2;
    {
      float a0 = 0.f, a1 = 0.f;
      if (gr < nRows) {
        int e0 = rp1[gr], e1 = rp1[gr + 1];
        int e = e0;
        for (; e + 2 <= e1; e += 2) {
          int s0 = cs1[e], s1 = cs1[e + 1];
          uint32 v0 = Xg1[(size_t)s0 * 64 + l];
          uint32 v1 = Xg1[(size_t)s1 * 64 + l];
          a0 += bflo(v0) + bflo(v1);
          a1 += bfhi(v0) + bfhi(v1);
        }
        if (e < e1) {
          uint32 v = Xg1[(size_t)cs1[e] * 64 + l];
          a0 += bflo(v); a1 += bfhi(v);
        }
      }
      L[r * TILE_DW + (l ^ swz)] = pack2(a0, a1);
    }
    if constexpr (HAS2) {
      float a0 = 0.f, a1 = 0.f;
      if (gr < nRows) {
        int e0 = rp2[gr], e1 = rp2[gr + 1];
        int e = e0;
        for (; e + 2 <= e1; e += 2) {
          int s0 = cs2[e], s1 = cs2[e + 1];
          uint32 v0 = Xg2[(size_t)s0 * 64 + l];
          uint32 v1 = Xg2[(size_t)s1 * 64 + l];
          a0 += bflo(v0) + bflo(v1);
          a1 += bfhi(v0) + bfhi(v1);
        }
        if (e < e1) {
          uint32 v = Xg2[(size_t)cs2[e] * 64 + l];
          a0 += bflo(v); a1 += bfhi(v);
        }
      }
      L[r * TILE_DW + ((64 + l) ^ swz)] = pack2(a0, a1);
    }
  }

  // ---- MFMA phase ----
  int row = l & 15, khi = l >> 4;
  int rswz = (row & 7) << 2;
  f32x4 acc[8] = {};
  // gathered k-steps (A from LDS)
  #pragma unroll
  for (int ks = 0; ks < KS_G; ++ks) {
    int d = (ks * 16 + khi * 4) ^ rswz;
    bf16x8 a = *(const bf16x8*)&L[row * TILE_DW + d];
    const bf16x8* Bp = BW + (size_t)(ks * 8) * 64 + l;
    #pragma unroll
    for (int nt = 0; nt < 8; ++nt) {
      bf16x8 b = Bp[(size_t)nt * 64];
      acc[nt] = __builtin_amdgcn_mfma_f32_16x16x32_bf16(a, b, acc[nt], 0, 0, 0);
    }
  }
  // root k-steps (A direct from global)
  {
    int gr = R0 + row;
    #pragma unroll
    for (int ks = 0; ks < 4; ++ks) {
      bf16x8 a{};
      if (gr < nRows) a = *(const bf16x8*)&Xr[(size_t)gr * 64 + ks * 16 + khi * 4];
      const bf16x8* Bp = BW + (size_t)((KS_G + ks) * 8) * 64 + l;
      #pragma unroll
      for (int nt = 0; nt < 8; ++nt) {
        bf16x8 b = Bp[(size_t)nt * 64];
        acc[nt] = __builtin_amdgcn_mfma_f32_16x16x32_bf16(a, b, acc[nt], 0, 0, 0);
      }
    }
  }

  // ---- epilogue: deg*u + bias, relu, stats, LDS repack, coalesced store ----
  int rl0 = khi * 4;
  float deg1v[4], deg2v[4];
  #pragma unroll
  for (int j = 0; j < 4; ++j) {
    int r = R0 + rl0 + j;
    deg1v[j] = (r < nRows) ? (float)(rp1[r + 1] - rp1[r]) : 0.f;
    if constexpr (HAS2) deg2v[j] = (r < nRows) ? (float)(rp2[r + 1] - rp2[r]) : 0.f;
    else deg2v[j] = 0.f;
  }
  ushort16* P = (ushort16*)L;   // repack: [16 rows][stride 136 ushorts]
  int c0 = l & 15;
  float ps[8], pq[8];
  #pragma unroll
  for (int nt = 0; nt < 8; ++nt) {
    int col = nt * 16 + c0;
    float bc = bias[col];
    float u1c = u1[col];
    float u2c = HAS2 ? u2[col] : 0.f;
    float s = 0.f, q = 0.f;
    #pragma unroll
    for (int j = 0; j < 4; ++j) {
      float v = acc[nt][j] + bc + deg1v[j] * u1c;
      if constexpr (HAS2) v += deg2v[j] * u2c;
      v = fmaxf(v, 0.f);
      if (R0 + rl0 + j < nRows) { s += v; q += v * v; }
      P[(rl0 + j) * 136 + col] = f2bf(v);
    }
    ps[nt] = s; pq[nt] = q;
  }

  // coalesced bf16 store via LDS repack
  #pragma unroll
  for (int rr = 0; rr < 4; ++rr) {
    int rloc = rr * 4 + khi;
    int grow = R0 + rloc;
    if (grow < nRows) {
      uint4 v = *(const uint4*)&P[rloc * 136 + c0 * 8];
      *(uint4*)&out[(size_t)grow * 64 + c0 * 4] = v;
    }
  }

  // BN stats: reduce across the 4 row-groups, striped atomics
  #pragma unroll
  for (int nt = 0; nt < 8; ++nt) {
    ps[nt] += __shfl_xor(ps[nt], 16); ps[nt] += __shfl_xor(ps[nt], 32);
    pq[nt] += __shfl_xor(pq[nt], 16); pq[nt] += __shfl_xor(pq[nt], 32);
  }
  if (l < 16) {
    float* S = statS + (size_t)(blockIdx.x & 63) * 128;
    float* Q = statQ + (size_t)(blockIdx.x & 63) * 128;
    #pragma unroll
    for (int nt = 0; nt < 8; ++nt) {
      unsafeAtomicAdd(&S[nt * 16 + l], ps[nt]);
      unsafeAtomicAdd(&Q[nt * 16 + l], pq[nt]);
    }
  }
}

// ---------------------------------------------------------------------------
// BN finalize from striped stats. stats layout: SA[64][128] QA SB QB
__global__ void bn_fin_k(const float* __restrict__ stats, const float* __restrict__ gamma,
                         const float* __restrict__ beta, float* __restrict__ ss,
                         float nA, float nB) {
  int t = threadIdx.x;
  if (t >= 256) return;
  int type = t >> 7, f = t & 127;
  const float* S = stats + (size_t)type * 16384;
  const float* Q = S + 8192;
  float s = 0.f, q = 0.f;
  for (int st = 0; st < 64; ++st) { s += S[st * 128 + f]; q += Q[st * 128 + f]; }
  float nN = type ? nB : nA;
  float mean = s / nN;
  float var = q / nN - mean * mean;
  float rstd = rsqrtf(var + 1e-5f);
  float sc = gamma[type * HF + f] * rstd;
  float sh = beta[type * HF + f] - mean * sc;
  ss[type * 256 + f] = sc;
  ss[type * 256 + 128 + f] = sh;
}

// ---------------------------------------------------------------------------
// pooling over sorted batch ids (bf16 x, lazy BN; shift folded via count)
__global__ __launch_bounds__(256) void pool_k(const uint32* __restrict__ x,
                                              const int* __restrict__ batch,
                                              const float* __restrict__ scale,
                                              const float* __restrict__ shift,
                                              float* __restrict__ pool, int nN) {
  int f2 = threadIdx.x & 31;   // feats 4f2..4f2+3
  int sub = threadIdx.x >> 5;  // 0..7
  int start = blockIdx.x * 1024;
  int end = min(start + 1024, nN);
  float4 sc = *(const float4*)&scale[f2 * 4];
  float4 sh = *(const float4*)&shift[f2 * 4];
  float a0 = 0.f, a1 = 0.f, a2 = 0.f, a3 = 0.f, cnt = 0.f;
  int cur = -1;
  for (int n = start + sub; n < end; n += 8) {
    int g = batch[n];
    if (g != cur) {
      if (cur >= 0) {
        float* bp = &pool[(size_t)cur * HF + f2 * 4];
        unsafeAtomicAdd(bp + 0, sc.x * a0 + cnt * sh.x);
        unsafeAtomicAdd(bp + 1, sc.y * a1 + cnt * sh.y);
        unsafeAtomicAdd(bp + 2, sc.z * a2 + cnt * sh.z);
        unsafeAtomicAdd(bp + 3, sc.w * a3 + cnt * sh.w);
      }
      a0 = a1 = a2 = a3 = 0.f; cnt = 0.f; cur = g;
    }
    uint2 v = *(const uint2*)&x[(size_t)n * 64 + f2 * 2];
    a0 += bflo(v.x); a1 += bfhi(v.x); a2 += bflo(v.y); a3 += bfhi(v.y);
    cnt += 1.f;
  }
  if (cur >= 0) {
    float* bp = &pool[(size_t)cur * HF + f2 * 4];
    unsafeAtomicAdd(bp + 0, sc.x * a0 + cnt * sh.x);
    unsafeAtomicAdd(bp + 1, sc.y * a1 + cnt * sh.y);
    unsafeAtomicAdd(bp + 2, sc.z * a2 + cnt * sh.z);
    unsafeAtomicAdd(bp + 3, sc.w * a3 + cnt * sh.w);
  }
}

__device__ inline int lowerb(const int* a, int n, int v) {
  int lo = 0, hi = n;
  while (lo < hi) { int m = (lo + hi) >> 1; if (a[m] < v) lo = m + 1; else hi = m; }
  return lo;
}

__global__ void counts_k(const int* __restrict__ ba, int nA, const int* __restrict__ bb, int nB,
                         float* __restrict__ counts, int Gn) {
  for (int g = threadIdx.x; g < Gn; g += blockDim.x) {
    int c = (lowerb(ba, nA, g + 1) - lowerb(ba, nA, g)) +
            (lowerb(bb, nB, g + 1) - lowerb(bb, nB, g));
    counts[g] = fmaxf((float)c, 1.f);
  }
}

__global__ void final_k(const float* __restrict__ pool, const float* __restrict__ counts,
                        const float* __restrict__ linW, const float* __restrict__ linb,
                        float* __restrict__ out, int Cn) {
  int g = blockIdx.x;
  int lane = threadIdx.x;
  float inv = 1.f / counts[g];
  float p0 = pool[(size_t)g * HF + lane] * inv;
  float p1 = pool[(size_t)g * HF + 64 + lane] * inv;
  for (int c = 0; c < Cn; ++c) {
    float t = p0 * linW[c * HF + lane] + p1 * linW[c * HF + 64 + lane];
    for (int off = 32; off > 0; off >>= 1) t += __shfl_down(t, off);
    if (lane == 0) out[g * Cn + c] = t + linb[c];
  }
}

// ---------------------------------------------------------------------------
extern "C" void kernel_launch(void* const* d_in, const int* in_sizes, int n_in,
                              void* d_out, int out_size, void* d_ws, size_t ws_size,
                              hipStream_t stream) {
  const float* x_a   = (const float*)d_in[0];
  const float* x_b   = (const float*)d_in[1];
  const float* Wrel  = (const float*)d_in[2];
  const float* brel  = (const float*)d_in[3];
  const float* Wroot = (const float*)d_in[4];
  const float* bn_g  = (const float*)d_in[5];
  const float* bn_b  = (const float*)d_in[6];
  const float* lin_W = (const float*)d_in[7];
  const float* lin_b = (const float*)d_in[8];
  const int* ei_aa   = (const int*)d_in[9];
  const int* ei_ab   = (const int*)d_in[10];
  const int* ei_ba   = (const int*)d_in[11];
  const int* batch_a = (const int*)d_in[12];
  const int* batch_b = (const int*)d_in[13];

  int Na  = in_sizes[0] / HF;
  int Nb  = in_sizes[1] / HF;
  int Eaa = in_sizes[9] / 2;
  int Eab = in_sizes[10] / 2;
  int Eba = in_sizes[11] / 2;
  int Cn  = in_sizes[7] / HF;
  int Gn  = out_size / Cn;

  size_t NHa = (size_t)Na * HF, NHb = (size_t)Nb * HF;
  char* base = (char*)d_ws;
  auto alignup = [](size_t x) { return (x + 255) & ~(size_t)255; };
  size_t off = 0;
  size_t oXA0 = off; off = alignup(off + NHa * 2);
  size_t oXA1 = off; off = alignup(off + NHa * 2);
  size_t oXB  = off; off = alignup(off + NHb * 2);
  size_t oRP  = off; off = alignup(off + ((size_t)(Na + 1) + (Nb + 1) + (Na + 1)) * 4);
  size_t oCUR = off; off = alignup(off + ((size_t)Na + Nb + Na) * 4);
  size_t oCS  = off; off = alignup(off + ((size_t)Eaa + Eab + Eba) * 4);
  size_t oBWA = off; off = alignup(off + (size_t)12 * 8 * 64 * 16);
  size_t oBWB = off; off = alignup(off + (size_t)8 * 8 * 64 * 16);
  size_t oUV  = off; off = alignup(off + 5 * 128 * 4);
  size_t oSS  = off; off = alignup(off + 512 * 4);
  size_t oST  = off; off = alignup(off + 32768 * 4);
  size_t oPOOL= off; off = alignup(off + (size_t)Gn * HF * 4);
  size_t oCNT = off; off = alignup(off + (size_t)Gn * 4);
  size_t need = off;

  if (ws_size < need) {
    diag_k<<<(out_size + 255) / 256, 256, 0, stream>>>(
        (float*)d_out, out_size, (float)((double)ws_size / 1048576.0));
    return;
  }

  uint32* XA0 = (uint32*)(base + oXA0);
  uint32* XA1 = (uint32*)(base + oXA1);
  uint32* XB  = (uint32*)(base + oXB);
  int* rp_aa = (int*)(base + oRP);
  int* rp_ab = rp_aa + (Na + 1);
  int* rp_ba = rp_ab + (Nb + 1);
  int* cur_aa = (int*)(base + oCUR);
  int* cur_ab = cur_aa + Na;
  int* cur_ba = cur_ab + Nb;
  int* cs_aa = (int*)(base + oCS);
  int* cs_ab = cs_aa + Eaa;
  int* cs_ba = cs_ab + Eab;
  ushort16* BWa = (ushort16*)(base + oBWA);
  ushort16* BWb = (ushort16*)(base + oBWB);
  float* uvec  = (float*)(base + oUV);
  float* ss    = (float*)(base + oSS);
  float* stats = (float*)(base + oST);
  float* pool  = (float*)(base + oPOOL);
  float* counts= (float*)(base + oCNT);

  float* ss_a = ss;
  float* ss_b = ss + 256;
  float* uaa = uvec, *uba = uvec + 128, *uab = uvec + 256;
  float* bias_a = uvec + 384, *bias_b = uvec + 512;
  float* SA = stats, *QA = stats + 8192, *SB = stats + 16384, *QB = stats + 24576;

  init_k<<<(512 + Gn * HF + 255) / 256, 256, 0, stream>>>(ss, pool, Gn);
  conv_k<<<((int)(NHa / 4) + 255) / 256, 256, 0, stream>>>(x_a, XA0, (int)(NHa / 4));
  conv_k<<<((int)(NHb / 4) + 255) / 256, 256, 0, stream>>>(x_b, XB, (int)(NHb / 4));

  hipMemsetAsync(rp_aa, 0, ((size_t)(Na + 1) + (Nb + 1) + (Na + 1)) * 4, stream);
  count_k<<<(Eaa + 255) / 256, 256, 0, stream>>>(ei_aa, Eaa, rp_aa);
  count_k<<<(Eab + 255) / 256, 256, 0, stream>>>(ei_ab, Eab, rp_ab);
  count_k<<<(Eba + 255) / 256, 256, 0, stream>>>(ei_ba, Eba, rp_ba);
  scan_k<<<1, 1024, 0, stream>>>(rp_aa, cur_aa, Na);
  scan_k<<<1, 1024, 0, stream>>>(rp_ab, cur_ab, Nb);
  scan_k<<<1, 1024, 0, stream>>>(rp_ba, cur_ba, Na);
  fill_k<<<(Eaa + 255) / 256, 256, 0, stream>>>(ei_aa, Eaa, cur_aa, cs_aa);
  fill_k<<<(Eab + 255) / 256, 256, 0, stream>>>(ei_ab, Eab, cur_ab, cs_ab);
  fill_k<<<(Eba + 255) / 256, 256, 0, stream>>>(ei_ba, Eba, cur_ba, cs_ba);

  uint32* xa_cur = XA0;
  uint32* xa_nxt = XA1;
  for (int l = 0; l < 3; ++l) {
    const float* Wrel_l  = Wrel  + (size_t)l * 3 * 16384;
    const float* Wroot_l = Wroot + (size_t)l * 3 * 16384;
    const float* brel_l  = brel  + (size_t)l * 3 * HF;

    prep2_k<<<128, 128, 0, stream>>>(Wrel_l, Wroot_l, brel_l, ss, BWa, BWb, uvec);
    hipMemsetAsync(stats, 0, 32768 * 4, stream);

    // type a (must precede type b: reads old XB)
    gg_k<true><<<(Na + 63) / 64, 256, 0, stream>>>(
        xa_cur, rp_aa, cs_aa, XB, rp_ba, cs_ba, xa_cur,
        (const bf16x8*)BWa, uaa, uba, bias_a, xa_nxt, SA, QA, Na);
    // type b (in-place on XB; gathers only from xa_cur)
    gg_k<false><<<(Nb + 63) / 64, 256, 0, stream>>>(
        xa_cur, rp_ab, cs_ab, nullptr, nullptr, nullptr, XB,
        (const bf16x8*)BWb, uab, nullptr, bias_b, XB, SB, QB, Nb);

    bn_fin_k<<<1, 256, 0, stream>>>(stats, bn_g, bn_b, ss, (float)Na, (float)Nb);

    uint32* t = xa_cur; xa_cur = xa_nxt; xa_nxt = t;
  }

  pool_k<<<(Na + 1023) / 1024, 256, 0, stream>>>(xa_cur, batch_a, ss_a, ss_a + 128, pool, Na);
  pool_k<<<(Nb + 1023) / 1024, 256, 0, stream>>>(XB, batch_b, ss_b, ss_b + 128, pool, Nb);
  counts_k<<<1, 256, 0, stream>>>(batch_a, Na, batch_b, Nb, counts, Gn);
  final_k<<<Gn, 64, 0, stream>>>(pool, counts, lin_W, lin_b, (float*)d_out, Cn);
}

// Round 4
// 1562.006 us; speedup vs baseline: 2.9407x; 1.8582x over previous
//
#include <hip/hip_runtime.h>
#include <hip/hip_bf16.h>

#define HF 128

typedef unsigned int uint32;
typedef unsigned short ushort16;
typedef float f32x4 __attribute__((ext_vector_type(4)));
typedef __bf16 bf16x8 __attribute__((ext_vector_type(8)));

// ---- bf16 helpers ----
__device__ __forceinline__ float bflo(uint32 u) { return __uint_as_float(u << 16); }
__device__ __forceinline__ float bfhi(uint32 u) { return __uint_as_float(u & 0xffff0000u); }
__device__ __forceinline__ ushort16 f2bf(float f) {
  uint32 u = __float_as_uint(f);
  return (ushort16)((u + 0x7fffu + ((u >> 16) & 1u)) >> 16);
}
__device__ __forceinline__ uint32 pack2(float lo, float hi) {
  return (uint32)f2bf(lo) | ((uint32)f2bf(hi) << 16);
}

// ---------------------------------------------------------------------------
__global__ void diag_k(float* __restrict__ out, int n, float val) {
  int i = blockIdx.x * 256 + threadIdx.x;
  if (i < n) out[i] = val;
}

// init: BN scale/shift identity for layer 0, zero pool
__global__ void init_k(float* __restrict__ ss, float* __restrict__ pool, int Gn) {
  int idx = blockIdx.x * 256 + threadIdx.x;
  if (idx < 512) ss[idx] = (idx < 128 || (idx >= 256 && idx < 384)) ? 1.f : 0.f;
  int p = idx - 512;
  if (p >= 0 && p < Gn * HF) pool[p] = 0.f;
}

// fp32 -> bf16 conversion
__global__ void conv_k(const float* __restrict__ in, uint32* __restrict__ out, int n4) {
  int i = blockIdx.x * 256 + threadIdx.x;
  if (i >= n4) return;
  float4 v = ((const float4*)in)[i];
  uint2 p;
  p.x = pack2(v.x, v.y);
  p.y = pack2(v.z, v.w);
  ((uint2*)out)[i] = p;
}

// ---------------------------------------------------------------------------
// CSR build: count -> hierarchical scan (3 passes) -> fill
__global__ void count_k(const int* __restrict__ ei, int E, int* __restrict__ rp) {
  int e = blockIdx.x * 256 + threadIdx.x;
  if (e < E) atomicAdd(&rp[ei[E + e]], 1);
}

// pass 1: per-1024-element block sums (coalesced int4 loads)
__global__ __launch_bounds__(256) void scan1_k(const int* __restrict__ rp, int N,
                                               int* __restrict__ bsum) {
  int b = blockIdx.x, t = threadIdx.x;
  int i = b * 1024 + t * 4;
  int s = 0;
  if (i + 3 < N) {
    int4 v = *(const int4*)&rp[i];
    s = v.x + v.y + v.z + v.w;
  } else {
    for (int j = 0; j < 4; ++j) if (i + j < N) s += rp[i + j];
  }
  __shared__ int sd[256];
  sd[t] = s;
  __syncthreads();
  for (int o = 128; o > 0; o >>= 1) {
    if (t < o) sd[t] += sd[t + o];
    __syncthreads();
  }
  if (t == 0) bsum[b] = sd[0];
}

// pass 2: exclusive scan of block sums (nb <= 1024)
__global__ __launch_bounds__(1024) void scan2_k(int* __restrict__ bsum, int nb) {
  __shared__ int sd[1024];
  int t = threadIdx.x;
  int v = (t < nb) ? bsum[t] : 0;
  sd[t] = v;
  __syncthreads();
  for (int o = 1; o < 1024; o <<= 1) {
    int x = (t >= o) ? sd[t - o] : 0;
    __syncthreads();
    sd[t] += x;
    __syncthreads();
  }
  if (t < nb) bsum[t] = sd[t] - v;   // exclusive prefix
}

// pass 3: per-block exclusive scan + global offset; writes rp, cur, rp[N]
__global__ __launch_bounds__(256) void scan3_k(int* __restrict__ rp, int* __restrict__ cur,
                                               const int* __restrict__ bsum, int N) {
  int b = blockIdx.x, t = threadIdx.x;
  int i = b * 1024 + t * 4;
  int c[4];
  #pragma unroll
  for (int j = 0; j < 4; ++j) c[j] = (i + j < N) ? rp[i + j] : 0;
  int tsum = c[0] + c[1] + c[2] + c[3];
  __shared__ int sd[256];
  sd[t] = tsum;
  __syncthreads();
  for (int o = 1; o < 256; o <<= 1) {
    int x = (t >= o) ? sd[t - o] : 0;
    __syncthreads();
    sd[t] += x;
    __syncthreads();
  }
  int off = bsum[b] + sd[t] - tsum;   // exclusive offset for this thread's 4 elems
  int p = off;
  #pragma unroll
  for (int j = 0; j < 4; ++j) {
    if (i + j < N) { rp[i + j] = p; cur[i + j] = p; }
    p += c[j];
  }
  if (i < N && N <= i + 4) rp[N] = off + tsum;   // grand total (zero-padded tail)
}

__global__ void fill_k(const int* __restrict__ ei, int E, int* __restrict__ cur,
                       int* __restrict__ cs) {
  int e = blockIdx.x * 256 + threadIdx.x;
  if (e >= E) return;
  int dst = ei[E + e];
  int pos = atomicAdd(&cur[dst], 1);
  cs[pos] = ei[e];
}

// ---------------------------------------------------------------------------
// per-layer prep: pack 5 weight mats into MFMA B-fragment order (bf16), with
// BN scale folded into k-columns; compute u-vectors (shift @ W^T) and biases.
// BWa: 12 ksteps (ks0-3: scA*Wrel0, ks4-7: scB*Wrel2, ks8-11: scA*(Wroot0+Wroot2))
// BWb: 8 ksteps  (ks0-3: scA*Wrel1, ks4-7: scB*Wroot1)
// uvec: [0]=uaa [1]=uba [2]=uab [3]=bias_a [4]=bias_b  (each 128 f32)
__global__ __launch_bounds__(128) void prep2_k(
    const float* __restrict__ Wrel_l, const float* __restrict__ Wroot_l,
    const float* __restrict__ brel_l, const float* __restrict__ ss,
    ushort16* __restrict__ BWa, ushort16* __restrict__ BWb,
    float* __restrict__ uvec) {
  __shared__ float red[128];
  int n = blockIdx.x, k = threadIdx.x;
  float scA = ss[k], shA = ss[128 + k], scB = ss[256 + k], shB = ss[384 + k];
  float w0  = Wrel_l[n * HF + k];
  float w1  = Wrel_l[16384 + n * HF + k];
  float w2  = Wrel_l[32768 + n * HF + k];
  float wr1 = Wroot_l[16384 + n * HF + k];
  float wrc = Wroot_l[n * HF + k] + Wroot_l[32768 + n * HF + k];

  int ksl = k >> 5;
  int lane = (n & 15) + (((k >> 3) & 3) << 4);
  int j = k & 7;
  int nt = n >> 4;
  auto put = [&](ushort16* B, int ksb, float v) {
    B[((size_t)((ksb + ksl) * 8 + nt) * 64 + lane) * 8 + j] = f2bf(v);
  };
  put(BWa, 0, scA * w0);
  put(BWa, 4, scB * w2);
  put(BWa, 8, scA * wrc);
  put(BWb, 0, scA * w1);
  put(BWb, 4, scB * wr1);

  auto reduce = [&](float v) -> float {
    red[k] = v;
    __syncthreads();
    for (int s = 64; s > 0; s >>= 1) {
      if (k < s) red[k] += red[k + s];
      __syncthreads();
    }
    float r = red[0];
    __syncthreads();
    return r;
  };
  float r0 = reduce(shA * w0);    // uaa
  float r1 = reduce(shB * w2);    // uba
  float r2 = reduce(shA * w1);    // uab
  float r3 = reduce(shA * wrc);   // bias_a extra
  float r4 = reduce(shB * wr1);   // bias_b extra
  if (k == 0) {
    uvec[n]       = r0;
    uvec[128 + n] = r1;
    uvec[256 + n] = r2;
    uvec[384 + n] = brel_l[n] + brel_l[256 + n] + r3;
    uvec[512 + n] = brel_l[128 + n] + r4;
  }
}

// ---------------------------------------------------------------------------
// fused gather + MFMA GEMM + epilogue. 256 threads = 4 independent waves,
// each owns 16 output rows. No barriers.
template <bool HAS2>
__global__ __launch_bounds__(256) void gg_k(
    const uint32* __restrict__ Xg1, const int* __restrict__ rp1, const int* __restrict__ cs1,
    const uint32* __restrict__ Xg2, const int* __restrict__ rp2, const int* __restrict__ cs2,
    const uint32* Xr,                       // no restrict: may alias out (type b)
    const bf16x8* __restrict__ BW,
    const float* __restrict__ u1, const float* __restrict__ u2,
    const float* __restrict__ bias,
    uint32* out,
    float* __restrict__ statS, float* __restrict__ statQ,
    int nRows) {
  constexpr int TILE_DW = HAS2 ? 128 : 64;   // dwords per LDS row (gather layout)
  constexpr int KS_G = HAS2 ? 8 : 4;         // gathered k-steps
  constexpr int WDW = HAS2 ? 2048 : 1088;    // per-wave LDS dwords
  __shared__ uint32 lds[4][WDW];
  int tid = threadIdx.x, wid = tid >> 6, l = tid & 63;
  int R0 = blockIdx.x * 64 + wid * 16;
  uint32* L = &lds[wid][0];

  // ---- gather phase: rows R0..R0+15, pure bf16 row-sum, swizzled LDS ----
  for (int r = 0; r < 16; ++r) {
    int gr = R0 + r;
    int swz = (r & 7) << 2;
    {
      float a0 = 0.f, a1 = 0.f;
      if (gr < nRows) {
        int e0 = rp1[gr], e1 = rp1[gr + 1];
        int e = e0;
        for (; e + 2 <= e1; e += 2) {
          int s0 = cs1[e], s1 = cs1[e + 1];
          uint32 v0 = Xg1[(size_t)s0 * 64 + l];
          uint32 v1 = Xg1[(size_t)s1 * 64 + l];
          a0 += bflo(v0) + bflo(v1);
          a1 += bfhi(v0) + bfhi(v1);
        }
        if (e < e1) {
          uint32 v = Xg1[(size_t)cs1[e] * 64 + l];
          a0 += bflo(v); a1 += bfhi(v);
        }
      }
      L[r * TILE_DW + (l ^ swz)] = pack2(a0, a1);
    }
    if constexpr (HAS2) {
      float a0 = 0.f, a1 = 0.f;
      if (gr < nRows) {
        int e0 = rp2[gr], e1 = rp2[gr + 1];
        int e = e0;
        for (; e + 2 <= e1; e += 2) {
          int s0 = cs2[e], s1 = cs2[e + 1];
          uint32 v0 = Xg2[(size_t)s0 * 64 + l];
          uint32 v1 = Xg2[(size_t)s1 * 64 + l];
          a0 += bflo(v0) + bflo(v1);
          a1 += bfhi(v0) + bfhi(v1);
        }
        if (e < e1) {
          uint32 v = Xg2[(size_t)cs2[e] * 64 + l];
          a0 += bflo(v); a1 += bfhi(v);
        }
      }
      L[r * TILE_DW + ((64 + l) ^ swz)] = pack2(a0, a1);
    }
  }

  // ---- MFMA phase ----
  int row = l & 15, khi = l >> 4;
  int rswz = (row & 7) << 2;
  f32x4 acc[8] = {};
  // gathered k-steps (A from LDS)
  #pragma unroll
  for (int ks = 0; ks < KS_G; ++ks) {
    int d = (ks * 16 + khi * 4) ^ rswz;
    bf16x8 a = *(const bf16x8*)&L[row * TILE_DW + d];
    const bf16x8* Bp = BW + (size_t)(ks * 8) * 64 + l;
    #pragma unroll
    for (int nt = 0; nt < 8; ++nt) {
      bf16x8 b = Bp[(size_t)nt * 64];
      acc[nt] = __builtin_amdgcn_mfma_f32_16x16x32_bf16(a, b, acc[nt], 0, 0, 0);
    }
  }
  // root k-steps (A direct from global)
  {
    int gr = R0 + row;
    #pragma unroll
    for (int ks = 0; ks < 4; ++ks) {
      bf16x8 a{};
      if (gr < nRows) a = *(const bf16x8*)&Xr[(size_t)gr * 64 + ks * 16 + khi * 4];
      const bf16x8* Bp = BW + (size_t)((KS_G + ks) * 8) * 64 + l;
      #pragma unroll
      for (int nt = 0; nt < 8; ++nt) {
        bf16x8 b = Bp[(size_t)nt * 64];
        acc[nt] = __builtin_amdgcn_mfma_f32_16x16x32_bf16(a, b, acc[nt], 0, 0, 0);
      }
    }
  }

  // ---- epilogue: deg*u + bias, relu, stats, LDS repack, coalesced store ----
  int rl0 = khi * 4;
  float deg1v[4], deg2v[4];
  #pragma unroll
  for (int j = 0; j < 4; ++j) {
    int r = R0 + rl0 + j;
    deg1v[j] = (r < nRows) ? (float)(rp1[r + 1] - rp1[r]) : 0.f;
    if constexpr (HAS2) deg2v[j] = (r < nRows) ? (float)(rp2[r + 1] - rp2[r]) : 0.f;
    else deg2v[j] = 0.f;
  }
  ushort16* P = (ushort16*)L;   // repack: [16 rows][stride 136 ushorts]
  int c0 = l & 15;
  float ps[8], pq[8];
  #pragma unroll
  for (int nt = 0; nt < 8; ++nt) {
    int col = nt * 16 + c0;
    float bc = bias[col];
    float u1c = u1[col];
    float u2c = HAS2 ? u2[col] : 0.f;
    float s = 0.f, q = 0.f;
    #pragma unroll
    for (int j = 0; j < 4; ++j) {
      float v = acc[nt][j] + bc + deg1v[j] * u1c;
      if constexpr (HAS2) v += deg2v[j] * u2c;
      v = fmaxf(v, 0.f);
      if (R0 + rl0 + j < nRows) { s += v; q += v * v; }
      P[(rl0 + j) * 136 + col] = f2bf(v);
    }
    ps[nt] = s; pq[nt] = q;
  }

  // coalesced bf16 store via LDS repack
  #pragma unroll
  for (int rr = 0; rr < 4; ++rr) {
    int rloc = rr * 4 + khi;
    int grow = R0 + rloc;
    if (grow < nRows) {
      uint4 v = *(const uint4*)&P[rloc * 136 + c0 * 8];
      *(uint4*)&out[(size_t)grow * 64 + c0 * 4] = v;
    }
  }

  // BN stats: reduce across the 4 row-groups, striped atomics
  #pragma unroll
  for (int nt = 0; nt < 8; ++nt) {
    ps[nt] += __shfl_xor(ps[nt], 16); ps[nt] += __shfl_xor(ps[nt], 32);
    pq[nt] += __shfl_xor(pq[nt], 16); pq[nt] += __shfl_xor(pq[nt], 32);
  }
  if (l < 16) {
    float* S = statS + (size_t)(blockIdx.x & 63) * 128;
    float* Q = statQ + (size_t)(blockIdx.x & 63) * 128;
    #pragma unroll
    for (int nt = 0; nt < 8; ++nt) {
      unsafeAtomicAdd(&S[nt * 16 + l], ps[nt]);
      unsafeAtomicAdd(&Q[nt * 16 + l], pq[nt]);
    }
  }
}

// ---------------------------------------------------------------------------
// BN finalize from striped stats. stats layout: SA[64][128] QA SB QB
__global__ void bn_fin_k(const float* __restrict__ stats, const float* __restrict__ gamma,
                         const float* __restrict__ beta, float* __restrict__ ss,
                         float nA, float nB) {
  int t = threadIdx.x;
  if (t >= 256) return;
  int type = t >> 7, f = t & 127;
  const float* S = stats + (size_t)type * 16384;
  const float* Q = S + 8192;
  float s = 0.f, q = 0.f;
  for (int st = 0; st < 64; ++st) { s += S[st * 128 + f]; q += Q[st * 128 + f]; }
  float nN = type ? nB : nA;
  float mean = s / nN;
  float var = q / nN - mean * mean;
  float rstd = rsqrtf(var + 1e-5f);
  float sc = gamma[type * HF + f] * rstd;
  float sh = beta[type * HF + f] - mean * sc;
  ss[type * 256 + f] = sc;
  ss[type * 256 + 128 + f] = sh;
}

// ---------------------------------------------------------------------------
// pooling over sorted batch ids (bf16 x, lazy BN; shift folded via count)
__global__ __launch_bounds__(256) void pool_k(const uint32* __restrict__ x,
                                              const int* __restrict__ batch,
                                              const float* __restrict__ scale,
                                              const float* __restrict__ shift,
                                              float* __restrict__ pool, int nN) {
  int f2 = threadIdx.x & 31;   // feats 4f2..4f2+3
  int sub = threadIdx.x >> 5;  // 0..7
  int start = blockIdx.x * 1024;
  int end = min(start + 1024, nN);
  float4 sc = *(const float4*)&scale[f2 * 4];
  float4 sh = *(const float4*)&shift[f2 * 4];
  float a0 = 0.f, a1 = 0.f, a2 = 0.f, a3 = 0.f, cnt = 0.f;
  int cur = -1;
  for (int n = start + sub; n < end; n += 8) {
    int g = batch[n];
    if (g != cur) {
      if (cur >= 0) {
        float* bp = &pool[(size_t)cur * HF + f2 * 4];
        unsafeAtomicAdd(bp + 0, sc.x * a0 + cnt * sh.x);
        unsafeAtomicAdd(bp + 1, sc.y * a1 + cnt * sh.y);
        unsafeAtomicAdd(bp + 2, sc.z * a2 + cnt * sh.z);
        unsafeAtomicAdd(bp + 3, sc.w * a3 + cnt * sh.w);
      }
      a0 = a1 = a2 = a3 = 0.f; cnt = 0.f; cur = g;
    }
    uint2 v = *(const uint2*)&x[(size_t)n * 64 + f2 * 2];
    a0 += bflo(v.x); a1 += bfhi(v.x); a2 += bflo(v.y); a3 += bfhi(v.y);
    cnt += 1.f;
  }
  if (cur >= 0) {
    float* bp = &pool[(size_t)cur * HF + f2 * 4];
    unsafeAtomicAdd(bp + 0, sc.x * a0 + cnt * sh.x);
    unsafeAtomicAdd(bp + 1, sc.y * a1 + cnt * sh.y);
    unsafeAtomicAdd(bp + 2, sc.z * a2 + cnt * sh.z);
    unsafeAtomicAdd(bp + 3, sc.w * a3 + cnt * sh.w);
  }
}

__device__ inline int lowerb(const int* a, int n, int v) {
  int lo = 0, hi = n;
  while (lo < hi) { int m = (lo + hi) >> 1; if (a[m] < v) lo = m + 1; else hi = m; }
  return lo;
}

__global__ void counts_k(const int* __restrict__ ba, int nA, const int* __restrict__ bb, int nB,
                         float* __restrict__ counts, int Gn) {
  for (int g = threadIdx.x; g < Gn; g += blockDim.x) {
    int c = (lowerb(ba, nA, g + 1) - lowerb(ba, nA, g)) +
            (lowerb(bb, nB, g + 1) - lowerb(bb, nB, g));
    counts[g] = fmaxf((float)c, 1.f);
  }
}

__global__ void final_k(const float* __restrict__ pool, const float* __restrict__ counts,
                        const float* __restrict__ linW, const float* __restrict__ linb,
                        float* __restrict__ out, int Cn) {
  int g = blockIdx.x;
  int lane = threadIdx.x;
  float inv = 1.f / counts[g];
  float p0 = pool[(size_t)g * HF + lane] * inv;
  float p1 = pool[(size_t)g * HF + 64 + lane] * inv;
  for (int c = 0; c < Cn; ++c) {
    float t = p0 * linW[c * HF + lane] + p1 * linW[c * HF + 64 + lane];
    for (int off = 32; off > 0; off >>= 1) t += __shfl_down(t, off);
    if (lane == 0) out[g * Cn + c] = t + linb[c];
  }
}

// ---------------------------------------------------------------------------
extern "C" void kernel_launch(void* const* d_in, const int* in_sizes, int n_in,
                              void* d_out, int out_size, void* d_ws, size_t ws_size,
                              hipStream_t stream) {
  const float* x_a   = (const float*)d_in[0];
  const float* x_b   = (const float*)d_in[1];
  const float* Wrel  = (const float*)d_in[2];
  const float* brel  = (const float*)d_in[3];
  const float* Wroot = (const float*)d_in[4];
  const float* bn_g  = (const float*)d_in[5];
  const float* bn_b  = (const float*)d_in[6];
  const float* lin_W = (const float*)d_in[7];
  const float* lin_b = (const float*)d_in[8];
  const int* ei_aa   = (const int*)d_in[9];
  const int* ei_ab   = (const int*)d_in[10];
  const int* ei_ba   = (const int*)d_in[11];
  const int* batch_a = (const int*)d_in[12];
  const int* batch_b = (const int*)d_in[13];

  int Na  = in_sizes[0] / HF;
  int Nb  = in_sizes[1] / HF;
  int Eaa = in_sizes[9] / 2;
  int Eab = in_sizes[10] / 2;
  int Eba = in_sizes[11] / 2;
  int Cn  = in_sizes[7] / HF;
  int Gn  = out_size / Cn;

  size_t NHa = (size_t)Na * HF, NHb = (size_t)Nb * HF;
  char* base = (char*)d_ws;
  auto alignup = [](size_t x) { return (x + 255) & ~(size_t)255; };
  size_t off = 0;
  size_t oXA0 = off; off = alignup(off + NHa * 2);
  size_t oXA1 = off; off = alignup(off + NHa * 2);
  size_t oXB  = off; off = alignup(off + NHb * 2);
  size_t oRP  = off; off = alignup(off + ((size_t)(Na + 1) + (Nb + 1) + (Na + 1)) * 4);
  size_t oCUR = off; off = alignup(off + ((size_t)Na + Nb + Na) * 4);
  size_t oCS  = off; off = alignup(off + ((size_t)Eaa + Eab + Eba) * 4);
  size_t oBWA = off; off = alignup(off + (size_t)12 * 8 * 64 * 16);
  size_t oBWB = off; off = alignup(off + (size_t)8 * 8 * 64 * 16);
  size_t oUV  = off; off = alignup(off + 5 * 128 * 4);
  size_t oSS  = off; off = alignup(off + 512 * 4);
  size_t oST  = off; off = alignup(off + 32768 * 4);
  size_t oBS  = off; off = alignup(off + 1024 * 4);
  size_t oPOOL= off; off = alignup(off + (size_t)Gn * HF * 4);
  size_t oCNT = off; off = alignup(off + (size_t)Gn * 4);
  size_t need = off;

  if (ws_size < need) {
    diag_k<<<(out_size + 255) / 256, 256, 0, stream>>>(
        (float*)d_out, out_size, (float)((double)ws_size / 1048576.0));
    return;
  }

  uint32* XA0 = (uint32*)(base + oXA0);
  uint32* XA1 = (uint32*)(base + oXA1);
  uint32* XB  = (uint32*)(base + oXB);
  int* rp_aa = (int*)(base + oRP);
  int* rp_ab = rp_aa + (Na + 1);
  int* rp_ba = rp_ab + (Nb + 1);
  int* cur_aa = (int*)(base + oCUR);
  int* cur_ab = cur_aa + Na;
  int* cur_ba = cur_ab + Nb;
  int* cs_aa = (int*)(base + oCS);
  int* cs_ab = cs_aa + Eaa;
  int* cs_ba = cs_ab + Eab;
  ushort16* BWa = (ushort16*)(base + oBWA);
  ushort16* BWb = (ushort16*)(base + oBWB);
  float* uvec  = (float*)(base + oUV);
  float* ss    = (float*)(base + oSS);
  float* stats = (float*)(base + oST);
  int* bsum    = (int*)(base + oBS);
  float* pool  = (float*)(base + oPOOL);
  float* counts= (float*)(base + oCNT);

  float* ss_a = ss;
  float* ss_b = ss + 256;
  float* uaa = uvec, *uba = uvec + 128, *uab = uvec + 256;
  float* bias_a = uvec + 384, *bias_b = uvec + 512;
  float* SA = stats, *QA = stats + 8192, *SB = stats + 16384, *QB = stats + 24576;

  init_k<<<(512 + Gn * HF + 255) / 256, 256, 0, stream>>>(ss, pool, Gn);
  conv_k<<<((int)(NHa / 4) + 255) / 256, 256, 0, stream>>>(x_a, XA0, (int)(NHa / 4));
  conv_k<<<((int)(NHb / 4) + 255) / 256, 256, 0, stream>>>(x_b, XB, (int)(NHb / 4));

  hipMemsetAsync(rp_aa, 0, ((size_t)(Na + 1) + (Nb + 1) + (Na + 1)) * 4, stream);
  count_k<<<(Eaa + 255) / 256, 256, 0, stream>>>(ei_aa, Eaa, rp_aa);
  count_k<<<(Eab + 255) / 256, 256, 0, stream>>>(ei_ab, Eab, rp_ab);
  count_k<<<(Eba + 255) / 256, 256, 0, stream>>>(ei_ba, Eba, rp_ba);

  int nb_a = (Na + 1023) / 1024;
  int nb_b = (Nb + 1023) / 1024;
  // hierarchical scans (sequential on stream; bsum reused)
  scan1_k<<<nb_a, 256, 0, stream>>>(rp_aa, Na, bsum);
  scan2_k<<<1, 1024, 0, stream>>>(bsum, nb_a);
  scan3_k<<<nb_a, 256, 0, stream>>>(rp_aa, cur_aa, bsum, Na);
  scan1_k<<<nb_b, 256, 0, stream>>>(rp_ab, Nb, bsum);
  scan2_k<<<1, 1024, 0, stream>>>(bsum, nb_b);
  scan3_k<<<nb_b, 256, 0, stream>>>(rp_ab, cur_ab, bsum, Nb);
  scan1_k<<<nb_a, 256, 0, stream>>>(rp_ba, Na, bsum);
  scan2_k<<<1, 1024, 0, stream>>>(bsum, nb_a);
  scan3_k<<<nb_a, 256, 0, stream>>>(rp_ba, cur_ba, bsum, Na);

  fill_k<<<(Eaa + 255) / 256, 256, 0, stream>>>(ei_aa, Eaa, cur_aa, cs_aa);
  fill_k<<<(Eab + 255) / 256, 256, 0, stream>>>(ei_ab, Eab, cur_ab, cs_ab);
  fill_k<<<(Eba + 255) / 256, 256, 0, stream>>>(ei_ba, Eba, cur_ba, cs_ba);

  uint32* xa_cur = XA0;
  uint32* xa_nxt = XA1;
  for (int l = 0; l < 3; ++l) {
    const float* Wrel_l  = Wrel  + (size_t)l * 3 * 16384;
    const float* Wroot_l = Wroot + (size_t)l * 3 * 16384;
    const float* brel_l  = brel  + (size_t)l * 3 * HF;

    prep2_k<<<128, 128, 0, stream>>>(Wrel_l, Wroot_l, brel_l, ss, BWa, BWb, uvec);
    hipMemsetAsync(stats, 0, 32768 * 4, stream);

    // type a (must precede type b: reads old XB)
    gg_k<true><<<(Na + 63) / 64, 256, 0, stream>>>(
        xa_cur, rp_aa, cs_aa, XB, rp_ba, cs_ba, xa_cur,
        (const bf16x8*)BWa, uaa, uba, bias_a, xa_nxt, SA, QA, Na);
    // type b (in-place on XB; gathers only from xa_cur)
    gg_k<false><<<(Nb + 63) / 64, 256, 0, stream>>>(
        xa_cur, rp_ab, cs_ab, nullptr, nullptr, nullptr, XB,
        (const bf16x8*)BWb, uab, nullptr, bias_b, XB, SB, QB, Nb);

    bn_fin_k<<<1, 256, 0, stream>>>(stats, bn_g, bn_b, ss, (float)Na, (float)Nb);

    uint32* t = xa_cur; xa_cur = xa_nxt; xa_nxt = t;
  }

  pool_k<<<(Na + 1023) / 1024, 256, 0, stream>>>(xa_cur, batch_a, ss_a, ss_a + 128, pool, Na);
  pool_k<<<(Nb + 1023) / 1024, 256, 0, stream>>>(XB, batch_b, ss_b, ss_b + 128, pool, Nb);
  counts_k<<<1, 256, 0, stream>>>(batch_a, Na, batch_b, Nb, counts, Gn);
  final_k<<<Gn, 64, 0, stream>>>(pool, counts, lin_W, lin_b, (float*)d_out, Cn);
}

// Round 5
// 1147.249 us; speedup vs baseline: 4.0039x; 1.3615x over previous
//
#include <hip/hip_runtime.h>
#include <hip/hip_bf16.h>

#define HF 128

typedef unsigned int uint32;
typedef unsigned short ushort16;
typedef float f32x4 __attribute__((ext_vector_type(4)));
typedef __bf16 bf16x8 __attribute__((ext_vector_type(8)));

// ---- bf16 helpers ----
__device__ __forceinline__ float bflo(uint32 u) { return __uint_as_float(u << 16); }
__device__ __forceinline__ float bfhi(uint32 u) { return __uint_as_float(u & 0xffff0000u); }
__device__ __forceinline__ ushort16 f2bf(float f) {
  uint32 u = __float_as_uint(f);
  return (ushort16)((u + 0x7fffu + ((u >> 16) & 1u)) >> 16);
}
__device__ __forceinline__ uint32 pack2(float lo, float hi) {
  return (uint32)f2bf(lo) | ((uint32)f2bf(hi) << 16);
}

// ---------------------------------------------------------------------------
__global__ void diag_k(float* __restrict__ out, int n, float val) {
  int i = blockIdx.x * 256 + threadIdx.x;
  if (i < n) out[i] = val;
}

// init: BN scale/shift identity for layer 0, zero pool
__global__ void init_k(float* __restrict__ ss, float* __restrict__ pool, int Gn) {
  int idx = blockIdx.x * 256 + threadIdx.x;
  if (idx < 512) ss[idx] = (idx < 128 || (idx >= 256 && idx < 384)) ? 1.f : 0.f;
  int p = idx - 512;
  if (p >= 0 && p < Gn * HF) pool[p] = 0.f;
}

// fp32 -> bf16 conversion
__global__ void conv_k(const float* __restrict__ in, uint32* __restrict__ out, int n4) {
  int i = blockIdx.x * 256 + threadIdx.x;
  if (i >= n4) return;
  float4 v = ((const float4*)in)[i];
  uint2 p;
  p.x = pack2(v.x, v.y);
  p.y = pack2(v.z, v.w);
  ((uint2*)out)[i] = p;
}

// ---------------------------------------------------------------------------
// CSR build: count -> hierarchical scan (3 passes) -> fill
__global__ void count_k(const int* __restrict__ ei, int E, int* __restrict__ rp) {
  int e = blockIdx.x * 256 + threadIdx.x;
  if (e < E) atomicAdd(&rp[ei[E + e]], 1);
}

// pass 1: per-1024-element block sums (coalesced int4 loads)
__global__ __launch_bounds__(256) void scan1_k(const int* __restrict__ rp, int N,
                                               int* __restrict__ bsum) {
  int b = blockIdx.x, t = threadIdx.x;
  int i = b * 1024 + t * 4;
  int s = 0;
  if (i + 3 < N) {
    int4 v = *(const int4*)&rp[i];
    s = v.x + v.y + v.z + v.w;
  } else {
    for (int j = 0; j < 4; ++j) if (i + j < N) s += rp[i + j];
  }
  __shared__ int sd[256];
  sd[t] = s;
  __syncthreads();
  for (int o = 128; o > 0; o >>= 1) {
    if (t < o) sd[t] += sd[t + o];
    __syncthreads();
  }
  if (t == 0) bsum[b] = sd[0];
}

// pass 2: exclusive scan of block sums (nb <= 1024)
__global__ __launch_bounds__(1024) void scan2_k(int* __restrict__ bsum, int nb) {
  __shared__ int sd[1024];
  int t = threadIdx.x;
  int v = (t < nb) ? bsum[t] : 0;
  sd[t] = v;
  __syncthreads();
  for (int o = 1; o < 1024; o <<= 1) {
    int x = (t >= o) ? sd[t - o] : 0;
    __syncthreads();
    sd[t] += x;
    __syncthreads();
  }
  if (t < nb) bsum[t] = sd[t] - v;   // exclusive prefix
}

// pass 3: per-block exclusive scan + global offset; writes rp, cur, rp[N]
__global__ __launch_bounds__(256) void scan3_k(int* __restrict__ rp, int* __restrict__ cur,
                                               const int* __restrict__ bsum, int N) {
  int b = blockIdx.x, t = threadIdx.x;
  int i = b * 1024 + t * 4;
  int c[4];
  #pragma unroll
  for (int j = 0; j < 4; ++j) c[j] = (i + j < N) ? rp[i + j] : 0;
  int tsum = c[0] + c[1] + c[2] + c[3];
  __shared__ int sd[256];
  sd[t] = tsum;
  __syncthreads();
  for (int o = 1; o < 256; o <<= 1) {
    int x = (t >= o) ? sd[t - o] : 0;
    __syncthreads();
    sd[t] += x;
    __syncthreads();
  }
  int off = bsum[b] + sd[t] - tsum;   // exclusive offset for this thread's 4 elems
  int p = off;
  #pragma unroll
  for (int j = 0; j < 4; ++j) {
    if (i + j < N) { rp[i + j] = p; cur[i + j] = p; }
    p += c[j];
  }
  if (i < N && N <= i + 4) rp[N] = off + tsum;   // grand total (zero-padded tail)
}

__global__ void fill_k(const int* __restrict__ ei, int E, int* __restrict__ cur,
                       int* __restrict__ cs) {
  int e = blockIdx.x * 256 + threadIdx.x;
  if (e >= E) return;
  int dst = ei[E + e];
  int pos = atomicAdd(&cur[dst], 1);
  cs[pos] = ei[e];
}

// ---------------------------------------------------------------------------
// per-layer prep: pack 5 weight mats into MFMA B-fragment order (bf16), with
// BN scale folded into k-columns; compute u-vectors (shift @ W^T) and biases.
// BWa: 12 ksteps (ks0-3: scA*Wrel0, ks4-7: scB*Wrel2, ks8-11: scA*(Wroot0+Wroot2))
// BWb: 8 ksteps  (ks0-3: scA*Wrel1, ks4-7: scB*Wroot1)
// uvec: [0]=uaa [1]=uba [2]=uab [3]=bias_a [4]=bias_b  (each 128 f32)
__global__ __launch_bounds__(128) void prep2_k(
    const float* __restrict__ Wrel_l, const float* __restrict__ Wroot_l,
    const float* __restrict__ brel_l, const float* __restrict__ ss,
    ushort16* __restrict__ BWa, ushort16* __restrict__ BWb,
    float* __restrict__ uvec) {
  __shared__ float red[128];
  int n = blockIdx.x, k = threadIdx.x;
  float scA = ss[k], shA = ss[128 + k], scB = ss[256 + k], shB = ss[384 + k];
  float w0  = Wrel_l[n * HF + k];
  float w1  = Wrel_l[16384 + n * HF + k];
  float w2  = Wrel_l[32768 + n * HF + k];
  float wr1 = Wroot_l[16384 + n * HF + k];
  float wrc = Wroot_l[n * HF + k] + Wroot_l[32768 + n * HF + k];

  int ksl = k >> 5;
  int lane = (n & 15) + (((k >> 3) & 3) << 4);
  int j = k & 7;
  int nt = n >> 4;
  auto put = [&](ushort16* B, int ksb, float v) {
    B[((size_t)((ksb + ksl) * 8 + nt) * 64 + lane) * 8 + j] = f2bf(v);
  };
  put(BWa, 0, scA * w0);
  put(BWa, 4, scB * w2);
  put(BWa, 8, scA * wrc);
  put(BWb, 0, scA * w1);
  put(BWb, 4, scB * wr1);

  auto reduce = [&](float v) -> float {
    red[k] = v;
    __syncthreads();
    for (int s = 64; s > 0; s >>= 1) {
      if (k < s) red[k] += red[k + s];
      __syncthreads();
    }
    float r = red[0];
    __syncthreads();
    return r;
  };
  float r0 = reduce(shA * w0);    // uaa
  float r1 = reduce(shB * w2);    // uba
  float r2 = reduce(shA * w1);    // uab
  float r3 = reduce(shA * wrc);   // bias_a extra
  float r4 = reduce(shB * wr1);   // bias_b extra
  if (k == 0) {
    uvec[n]       = r0;
    uvec[128 + n] = r1;
    uvec[256 + n] = r2;
    uvec[384 + n] = brel_l[n] + brel_l[256 + n] + r3;
    uvec[512 + n] = brel_l[128 + n] + r4;
  }
}

// ---------------------------------------------------------------------------
// fused gather + MFMA GEMM + epilogue. 256 threads = 4 independent waves,
// each owns 16 output rows. No barriers.
// Gather: wave split into 4x16-lane groups; group g owns rows rr*4+g; each
// lane loads dwordx4 (16B) chunks => 4 rows' edge chains concurrently, 4x MLP.
template <bool HAS2>
__global__ __launch_bounds__(256) void gg_k(
    const uint32* __restrict__ Xg1, const int* __restrict__ rp1, const int* __restrict__ cs1,
    const uint32* __restrict__ Xg2, const int* __restrict__ rp2, const int* __restrict__ cs2,
    const uint32* Xr,                       // no restrict: may alias out (type b)
    const bf16x8* __restrict__ BW,
    const float* __restrict__ u1, const float* __restrict__ u2,
    const float* __restrict__ bias,
    uint32* out,
    float* __restrict__ statS, float* __restrict__ statQ,
    int nRows) {
  constexpr int KS_G = HAS2 ? 8 : 4;         // gathered k-steps
  constexpr int WDW = HAS2 ? 2048 : 1088;    // per-wave LDS dwords
  __shared__ uint32 lds[4][WDW];
  int tid = threadIdx.x, wid = tid >> 6, l = tid & 63;
  int R0 = blockIdx.x * 64 + wid * 16;
  uint32* L = &lds[wid][0];                  // tile0 @0, tile1 @1024 (HAS2)
  int grp = l >> 4, sub = l & 15;
  int row = l & 15, khi = l >> 4;

  // ---- root prefetch: in flight during the whole gather phase ----
  int grr = R0 + row;
  bf16x8 rt[4];
  #pragma unroll
  for (int ks = 0; ks < 4; ++ks) {
    rt[ks] = bf16x8{};
    if (grr < nRows)
      rt[ks] = *(const bf16x8*)&Xr[(size_t)grr * 64 + ks * 16 + khi * 4];
  }

  // ---- gather phase: group grp builds rows rr*4+grp; lane = 16B chunk sub ----
  #pragma unroll
  for (int rr = 0; rr < 4; ++rr) {
    int r = rr * 4 + grp;
    int gr = R0 + r;
    int dstOff = r * 64 + ((sub ^ (r & 7)) << 2);   // swizzled dword offset
    {
      float a0=0.f,a1=0.f,a2=0.f,a3=0.f,a4=0.f,a5=0.f,a6=0.f,a7=0.f;
      if (gr < nRows) {
        int e0 = rp1[gr], e1 = rp1[gr + 1];
        int e = e0;
        for (; e + 2 <= e1; e += 2) {
          int s0 = cs1[e], s1 = cs1[e + 1];
          uint4 v0 = *(const uint4*)&Xg1[(size_t)s0 * 64 + sub * 4];
          uint4 v1 = *(const uint4*)&Xg1[(size_t)s1 * 64 + sub * 4];
          a0 += bflo(v0.x) + bflo(v1.x); a1 += bfhi(v0.x) + bfhi(v1.x);
          a2 += bflo(v0.y) + bflo(v1.y); a3 += bfhi(v0.y) + bfhi(v1.y);
          a4 += bflo(v0.z) + bflo(v1.z); a5 += bfhi(v0.z) + bfhi(v1.z);
          a6 += bflo(v0.w) + bflo(v1.w); a7 += bfhi(v0.w) + bfhi(v1.w);
        }
        if (e < e1) {
          uint4 v = *(const uint4*)&Xg1[(size_t)cs1[e] * 64 + sub * 4];
          a0 += bflo(v.x); a1 += bfhi(v.x); a2 += bflo(v.y); a3 += bfhi(v.y);
          a4 += bflo(v.z); a5 += bfhi(v.z); a6 += bflo(v.w); a7 += bfhi(v.w);
        }
      }
      uint4 p;
      p.x = pack2(a0, a1); p.y = pack2(a2, a3);
      p.z = pack2(a4, a5); p.w = pack2(a6, a7);
      *(uint4*)&L[dstOff] = p;
    }
    if constexpr (HAS2) {
      float a0=0.f,a1=0.f,a2=0.f,a3=0.f,a4=0.f,a5=0.f,a6=0.f,a7=0.f;
      if (gr < nRows) {
        int e0 = rp2[gr], e1 = rp2[gr + 1];
        int e = e0;
        for (; e + 2 <= e1; e += 2) {
          int s0 = cs2[e], s1 = cs2[e + 1];
          uint4 v0 = *(const uint4*)&Xg2[(size_t)s0 * 64 + sub * 4];
          uint4 v1 = *(const uint4*)&Xg2[(size_t)s1 * 64 + sub * 4];
          a0 += bflo(v0.x) + bflo(v1.x); a1 += bfhi(v0.x) + bfhi(v1.x);
          a2 += bflo(v0.y) + bflo(v1.y); a3 += bfhi(v0.y) + bfhi(v1.y);
          a4 += bflo(v0.z) + bflo(v1.z); a5 += bfhi(v0.z) + bfhi(v1.z);
          a6 += bflo(v0.w) + bflo(v1.w); a7 += bfhi(v0.w) + bfhi(v1.w);
        }
        if (e < e1) {
          uint4 v = *(const uint4*)&Xg2[(size_t)cs2[e] * 64 + sub * 4];
          a0 += bflo(v.x); a1 += bfhi(v.x); a2 += bflo(v.y); a3 += bfhi(v.y);
          a4 += bflo(v.z); a5 += bfhi(v.z); a6 += bflo(v.w); a7 += bfhi(v.w);
        }
      }
      uint4 p;
      p.x = pack2(a0, a1); p.y = pack2(a2, a3);
      p.z = pack2(a4, a5); p.w = pack2(a6, a7);
      *(uint4*)&L[1024 + dstOff] = p;
    }
  }
  // per-wave LDS; in-wave ds ordering — no barrier needed

  // ---- MFMA phase ----
  f32x4 acc[8] = {};
  #pragma unroll
  for (int ks = 0; ks < 4; ++ks) {
    int d = row * 64 + (((ks * 4 + khi) ^ (row & 7)) << 2);
    bf16x8 a = *(const bf16x8*)&L[d];
    const bf16x8* Bp = BW + (size_t)(ks * 8) * 64 + l;
    #pragma unroll
    for (int nt = 0; nt < 8; ++nt) {
      bf16x8 b = Bp[(size_t)nt * 64];
      acc[nt] = __builtin_amdgcn_mfma_f32_16x16x32_bf16(a, b, acc[nt], 0, 0, 0);
    }
  }
  if constexpr (HAS2) {
    #pragma unroll
    for (int ks = 0; ks < 4; ++ks) {
      int d = 1024 + row * 64 + (((ks * 4 + khi) ^ (row & 7)) << 2);
      bf16x8 a = *(const bf16x8*)&L[d];
      const bf16x8* Bp = BW + (size_t)((4 + ks) * 8) * 64 + l;
      #pragma unroll
      for (int nt = 0; nt < 8; ++nt) {
        bf16x8 b = Bp[(size_t)nt * 64];
        acc[nt] = __builtin_amdgcn_mfma_f32_16x16x32_bf16(a, b, acc[nt], 0, 0, 0);
      }
    }
  }
  #pragma unroll
  for (int ks = 0; ks < 4; ++ks) {
    const bf16x8* Bp = BW + (size_t)((KS_G + ks) * 8) * 64 + l;
    #pragma unroll
    for (int nt = 0; nt < 8; ++nt) {
      bf16x8 b = Bp[(size_t)nt * 64];
      acc[nt] = __builtin_amdgcn_mfma_f32_16x16x32_bf16(rt[ks], b, acc[nt], 0, 0, 0);
    }
  }

  // ---- epilogue: deg*u + bias, relu, stats, LDS repack, coalesced store ----
  int rl0 = khi * 4;
  float deg1v[4], deg2v[4];
  #pragma unroll
  for (int j = 0; j < 4; ++j) {
    int r = R0 + rl0 + j;
    deg1v[j] = (r < nRows) ? (float)(rp1[r + 1] - rp1[r]) : 0.f;
    if constexpr (HAS2) deg2v[j] = (r < nRows) ? (float)(rp2[r + 1] - rp2[r]) : 0.f;
    else deg2v[j] = 0.f;
  }
  ushort16* P = (ushort16*)L;   // repack: [16 rows][stride 136 ushorts]
  int c0 = l & 15;
  float ps[8], pq[8];
  #pragma unroll
  for (int nt = 0; nt < 8; ++nt) {
    int col = nt * 16 + c0;
    float bc = bias[col];
    float u1c = u1[col];
    float u2c = HAS2 ? u2[col] : 0.f;
    float s = 0.f, q = 0.f;
    #pragma unroll
    for (int j = 0; j < 4; ++j) {
      float v = acc[nt][j] + bc + deg1v[j] * u1c;
      if constexpr (HAS2) v += deg2v[j] * u2c;
      v = fmaxf(v, 0.f);
      if (R0 + rl0 + j < nRows) { s += v; q += v * v; }
      P[(rl0 + j) * 136 + col] = f2bf(v);
    }
    ps[nt] = s; pq[nt] = q;
  }

  // coalesced bf16 store via LDS repack
  #pragma unroll
  for (int rr = 0; rr < 4; ++rr) {
    int rloc = rr * 4 + khi;
    int grow = R0 + rloc;
    if (grow < nRows) {
      uint4 v = *(const uint4*)&P[rloc * 136 + c0 * 8];
      *(uint4*)&out[(size_t)grow * 64 + c0 * 4] = v;
    }
  }

  // BN stats: reduce across the 4 row-groups, striped atomics
  #pragma unroll
  for (int nt = 0; nt < 8; ++nt) {
    ps[nt] += __shfl_xor(ps[nt], 16); ps[nt] += __shfl_xor(ps[nt], 32);
    pq[nt] += __shfl_xor(pq[nt], 16); pq[nt] += __shfl_xor(pq[nt], 32);
  }
  if (l < 16) {
    float* S = statS + (size_t)(blockIdx.x & 63) * 128;
    float* Q = statQ + (size_t)(blockIdx.x & 63) * 128;
    #pragma unroll
    for (int nt = 0; nt < 8; ++nt) {
      unsafeAtomicAdd(&S[nt * 16 + l], ps[nt]);
      unsafeAtomicAdd(&Q[nt * 16 + l], pq[nt]);
    }
  }
}

// ---------------------------------------------------------------------------
// BN finalize from striped stats. stats layout: SA[64][128] QA SB QB
__global__ void bn_fin_k(const float* __restrict__ stats, const float* __restrict__ gamma,
                         const float* __restrict__ beta, float* __restrict__ ss,
                         float nA, float nB) {
  int t = threadIdx.x;
  if (t >= 256) return;
  int type = t >> 7, f = t & 127;
  const float* S = stats + (size_t)type * 16384;
  const float* Q = S + 8192;
  float s = 0.f, q = 0.f;
  for (int st = 0; st < 64; ++st) { s += S[st * 128 + f]; q += Q[st * 128 + f]; }
  float nN = type ? nB : nA;
  float mean = s / nN;
  float var = q / nN - mean * mean;
  float rstd = rsqrtf(var + 1e-5f);
  float sc = gamma[type * HF + f] * rstd;
  float sh = beta[type * HF + f] - mean * sc;
  ss[type * 256 + f] = sc;
  ss[type * 256 + 128 + f] = sh;
}

// ---------------------------------------------------------------------------
// pooling over sorted batch ids (bf16 x, lazy BN; shift folded via count)
__global__ __launch_bounds__(256) void pool_k(const uint32* __restrict__ x,
                                              const int* __restrict__ batch,
                                              const float* __restrict__ scale,
                                              const float* __restrict__ shift,
                                              float* __restrict__ pool, int nN) {
  int f2 = threadIdx.x & 31;   // feats 4f2..4f2+3
  int sub = threadIdx.x >> 5;  // 0..7
  int start = blockIdx.x * 1024;
  int end = min(start + 1024, nN);
  float4 sc = *(const float4*)&scale[f2 * 4];
  float4 sh = *(const float4*)&shift[f2 * 4];
  float a0 = 0.f, a1 = 0.f, a2 = 0.f, a3 = 0.f, cnt = 0.f;
  int cur = -1;
  for (int n = start + sub; n < end; n += 8) {
    int g = batch[n];
    if (g != cur) {
      if (cur >= 0) {
        float* bp = &pool[(size_t)cur * HF + f2 * 4];
        unsafeAtomicAdd(bp + 0, sc.x * a0 + cnt * sh.x);
        unsafeAtomicAdd(bp + 1, sc.y * a1 + cnt * sh.y);
        unsafeAtomicAdd(bp + 2, sc.z * a2 + cnt * sh.z);
        unsafeAtomicAdd(bp + 3, sc.w * a3 + cnt * sh.w);
      }
      a0 = a1 = a2 = a3 = 0.f; cnt = 0.f; cur = g;
    }
    uint2 v = *(const uint2*)&x[(size_t)n * 64 + f2 * 2];
    a0 += bflo(v.x); a1 += bfhi(v.x); a2 += bflo(v.y); a3 += bfhi(v.y);
    cnt += 1.f;
  }
  if (cur >= 0) {
    float* bp = &pool[(size_t)cur * HF + f2 * 4];
    unsafeAtomicAdd(bp + 0, sc.x * a0 + cnt * sh.x);
    unsafeAtomicAdd(bp + 1, sc.y * a1 + cnt * sh.y);
    unsafeAtomicAdd(bp + 2, sc.z * a2 + cnt * sh.z);
    unsafeAtomicAdd(bp + 3, sc.w * a3 + cnt * sh.w);
  }
}

__device__ inline int lowerb(const int* a, int n, int v) {
  int lo = 0, hi = n;
  while (lo < hi) { int m = (lo + hi) >> 1; if (a[m] < v) lo = m + 1; else hi = m; }
  return lo;
}

__global__ void counts_k(const int* __restrict__ ba, int nA, const int* __restrict__ bb, int nB,
                         float* __restrict__ counts, int Gn) {
  for (int g = threadIdx.x; g < Gn; g += blockDim.x) {
    int c = (lowerb(ba, nA, g + 1) - lowerb(ba, nA, g)) +
            (lowerb(bb, nB, g + 1) - lowerb(bb, nB, g));
    counts[g] = fmaxf((float)c, 1.f);
  }
}

__global__ void final_k(const float* __restrict__ pool, const float* __restrict__ counts,
                        const float* __restrict__ linW, const float* __restrict__ linb,
                        float* __restrict__ out, int Cn) {
  int g = blockIdx.x;
  int lane = threadIdx.x;
  float inv = 1.f / counts[g];
  float p0 = pool[(size_t)g * HF + lane] * inv;
  float p1 = pool[(size_t)g * HF + 64 + lane] * inv;
  for (int c = 0; c < Cn; ++c) {
    float t = p0 * linW[c * HF + lane] + p1 * linW[c * HF + 64 + lane];
    for (int off = 32; off > 0; off >>= 1) t += __shfl_down(t, off);
    if (lane == 0) out[g * Cn + c] = t + linb[c];
  }
}

// ---------------------------------------------------------------------------
extern "C" void kernel_launch(void* const* d_in, const int* in_sizes, int n_in,
                              void* d_out, int out_size, void* d_ws, size_t ws_size,
                              hipStream_t stream) {
  const float* x_a   = (const float*)d_in[0];
  const float* x_b   = (const float*)d_in[1];
  const float* Wrel  = (const float*)d_in[2];
  const float* brel  = (const float*)d_in[3];
  const float* Wroot = (const float*)d_in[4];
  const float* bn_g  = (const float*)d_in[5];
  const float* bn_b  = (const float*)d_in[6];
  const float* lin_W = (const float*)d_in[7];
  const float* lin_b = (const float*)d_in[8];
  const int* ei_aa   = (const int*)d_in[9];
  const int* ei_ab   = (const int*)d_in[10];
  const int* ei_ba   = (const int*)d_in[11];
  const int* batch_a = (const int*)d_in[12];
  const int* batch_b = (const int*)d_in[13];

  int Na  = in_sizes[0] / HF;
  int Nb  = in_sizes[1] / HF;
  int Eaa = in_sizes[9] / 2;
  int Eab = in_sizes[10] / 2;
  int Eba = in_sizes[11] / 2;
  int Cn  = in_sizes[7] / HF;
  int Gn  = out_size / Cn;

  size_t NHa = (size_t)Na * HF, NHb = (size_t)Nb * HF;
  char* base = (char*)d_ws;
  auto alignup = [](size_t x) { return (x + 255) & ~(size_t)255; };
  size_t off = 0;
  size_t oXA0 = off; off = alignup(off + NHa * 2);
  size_t oXA1 = off; off = alignup(off + NHa * 2);
  size_t oXB  = off; off = alignup(off + NHb * 2);
  size_t oRP  = off; off = alignup(off + ((size_t)(Na + 1) + (Nb + 1) + (Na + 1)) * 4);
  size_t oCUR = off; off = alignup(off + ((size_t)Na + Nb + Na) * 4);
  size_t oCS  = off; off = alignup(off + ((size_t)Eaa + Eab + Eba) * 4);
  size_t oBWA = off; off = alignup(off + (size_t)12 * 8 * 64 * 16);
  size_t oBWB = off; off = alignup(off + (size_t)8 * 8 * 64 * 16);
  size_t oUV  = off; off = alignup(off + 5 * 128 * 4);
  size_t oSS  = off; off = alignup(off + 512 * 4);
  size_t oST  = off; off = alignup(off + 32768 * 4);
  size_t oBS  = off; off = alignup(off + 1024 * 4);
  size_t oPOOL= off; off = alignup(off + (size_t)Gn * HF * 4);
  size_t oCNT = off; off = alignup(off + (size_t)Gn * 4);
  size_t need = off;

  if (ws_size < need) {
    diag_k<<<(out_size + 255) / 256, 256, 0, stream>>>(
        (float*)d_out, out_size, (float)((double)ws_size / 1048576.0));
    return;
  }

  uint32* XA0 = (uint32*)(base + oXA0);
  uint32* XA1 = (uint32*)(base + oXA1);
  uint32* XB  = (uint32*)(base + oXB);
  int* rp_aa = (int*)(base + oRP);
  int* rp_ab = rp_aa + (Na + 1);
  int* rp_ba = rp_ab + (Nb + 1);
  int* cur_aa = (int*)(base + oCUR);
  int* cur_ab = cur_aa + Na;
  int* cur_ba = cur_ab + Nb;
  int* cs_aa = (int*)(base + oCS);
  int* cs_ab = cs_aa + Eaa;
  int* cs_ba = cs_ab + Eab;
  ushort16* BWa = (ushort16*)(base + oBWA);
  ushort16* BWb = (ushort16*)(base + oBWB);
  float* uvec  = (float*)(base + oUV);
  float* ss    = (float*)(base + oSS);
  float* stats = (float*)(base + oST);
  int* bsum    = (int*)(base + oBS);
  float* pool  = (float*)(base + oPOOL);
  float* counts= (float*)(base + oCNT);

  float* ss_a = ss;
  float* ss_b = ss + 256;
  float* uaa = uvec, *uba = uvec + 128, *uab = uvec + 256;
  float* bias_a = uvec + 384, *bias_b = uvec + 512;
  float* SA = stats, *QA = stats + 8192, *SB = stats + 16384, *QB = stats + 24576;

  init_k<<<(512 + Gn * HF + 255) / 256, 256, 0, stream>>>(ss, pool, Gn);
  conv_k<<<((int)(NHa / 4) + 255) / 256, 256, 0, stream>>>(x_a, XA0, (int)(NHa / 4));
  conv_k<<<((int)(NHb / 4) + 255) / 256, 256, 0, stream>>>(x_b, XB, (int)(NHb / 4));

  hipMemsetAsync(rp_aa, 0, ((size_t)(Na + 1) + (Nb + 1) + (Na + 1)) * 4, stream);
  count_k<<<(Eaa + 255) / 256, 256, 0, stream>>>(ei_aa, Eaa, rp_aa);
  count_k<<<(Eab + 255) / 256, 256, 0, stream>>>(ei_ab, Eab, rp_ab);
  count_k<<<(Eba + 255) / 256, 256, 0, stream>>>(ei_ba, Eba, rp_ba);

  int nb_a = (Na + 1023) / 1024;
  int nb_b = (Nb + 1023) / 1024;
  scan1_k<<<nb_a, 256, 0, stream>>>(rp_aa, Na, bsum);
  scan2_k<<<1, 1024, 0, stream>>>(bsum, nb_a);
  scan3_k<<<nb_a, 256, 0, stream>>>(rp_aa, cur_aa, bsum, Na);
  scan1_k<<<nb_b, 256, 0, stream>>>(rp_ab, Nb, bsum);
  scan2_k<<<1, 1024, 0, stream>>>(bsum, nb_b);
  scan3_k<<<nb_b, 256, 0, stream>>>(rp_ab, cur_ab, bsum, Nb);
  scan1_k<<<nb_a, 256, 0, stream>>>(rp_ba, Na, bsum);
  scan2_k<<<1, 1024, 0, stream>>>(bsum, nb_a);
  scan3_k<<<nb_a, 256, 0, stream>>>(rp_ba, cur_ba, bsum, Na);

  fill_k<<<(Eaa + 255) / 256, 256, 0, stream>>>(ei_aa, Eaa, cur_aa, cs_aa);
  fill_k<<<(Eab + 255) / 256, 256, 0, stream>>>(ei_ab, Eab, cur_ab, cs_ab);
  fill_k<<<(Eba + 255) / 256, 256, 0, stream>>>(ei_ba, Eba, cur_ba, cs_ba);

  uint32* xa_cur = XA0;
  uint32* xa_nxt = XA1;
  for (int l = 0; l < 3; ++l) {
    const float* Wrel_l  = Wrel  + (size_t)l * 3 * 16384;
    const float* Wroot_l = Wroot + (size_t)l * 3 * 16384;
    const float* brel_l  = brel  + (size_t)l * 3 * HF;

    prep2_k<<<128, 128, 0, stream>>>(Wrel_l, Wroot_l, brel_l, ss, BWa, BWb, uvec);
    hipMemsetAsync(stats, 0, 32768 * 4, stream);

    // type a (must precede type b: reads old XB)
    gg_k<true><<<(Na + 63) / 64, 256, 0, stream>>>(
        xa_cur, rp_aa, cs_aa, XB, rp_ba, cs_ba, xa_cur,
        (const bf16x8*)BWa, uaa, uba, bias_a, xa_nxt, SA, QA, Na);
    // type b (in-place on XB; gathers only from xa_cur)
    gg_k<false><<<(Nb + 63) / 64, 256, 0, stream>>>(
        xa_cur, rp_ab, cs_ab, nullptr, nullptr, nullptr, XB,
        (const bf16x8*)BWb, uab, nullptr, bias_b, XB, SB, QB, Nb);

    bn_fin_k<<<1, 256, 0, stream>>>(stats, bn_g, bn_b, ss, (float)Na, (float)Nb);

    uint32* t = xa_cur; xa_cur = xa_nxt; xa_nxt = t;
  }

  pool_k<<<(Na + 1023) / 1024, 256, 0, stream>>>(xa_cur, batch_a, ss_a, ss_a + 128, pool, Na);
  pool_k<<<(Nb + 1023) / 1024, 256, 0, stream>>>(XB, batch_b, ss_b, ss_b + 128, pool, Nb);
  counts_k<<<1, 256, 0, stream>>>(batch_a, Na, batch_b, Nb, counts, Gn);
  final_k<<<Gn, 64, 0, stream>>>(pool, counts, lin_W, lin_b, (float*)d_out, Cn);
}